// Round 1
// baseline (6624.686 us; speedup 1.0000x reference)
//
#include <hip/hip_runtime.h>

// RNN_M2M: bidirectional LSTM encoder (T=168,B=256,F=128,H=512) + autoregressive
// LSTM decoder (hidden 1024, 48 steps) + scalar FC. One persistent cooperative
// kernel with a custom tree grid-barrier; fp16 MFMA (16x16x32), fp32 accum.

constexpr int B_ = 256, T_ = 168, F_ = 128, H_ = 512, L_ = 48;
constexpr int KE = F_ + H_;   // 640  (combined [x|h] K for encoder)
constexpr int HD = 1024;      // decoder hidden
constexpr int GE = 4 * H_;    // 2048 encoder gate rows per dir
constexpr int GD = 4 * HD;    // 4096 decoder gate rows
constexpr int EPAD = KE + 8;  // LDS row stride (halves): 2-way bank aliasing only
constexpr int DPAD = HD + 8;

// workspace layout (bytes)
constexpr size_t OFF_BAR = 0;                                        // 4KB barrier
constexpr size_t OFF_WCF = 4096;                                     // enc fwd [Wih|Whh] fp16 [2048][640]
constexpr size_t OFF_WCB = OFF_WCF + (size_t)GE * KE * 2;            // enc bwd
constexpr size_t OFF_WD  = OFF_WCB + (size_t)GE * KE * 2;            // dec Whh fp16 [4096][1024]
constexpr size_t OFF_BF  = OFF_WD  + (size_t)GD * HD * 2;            // enc fwd bias f32 [2048]
constexpr size_t OFF_BB  = OFF_BF  + (size_t)GE * 4;
constexpr size_t OFF_BD  = OFF_BB  + (size_t)GE * 4;                 // dec bias f32 [4096]
constexpr size_t OFF_WIH = OFF_BD  + (size_t)GD * 4;                 // dec Wih col f32 [4096]
constexpr size_t OFF_XH  = OFF_WIH + (size_t)GD * 4;                 // x fp16 [T][B][F]
constexpr size_t OFF_HE  = OFF_XH  + (size_t)T_ * B_ * F_ * 2;       // enc h fp16 [2 par][2 dir][B][H]
constexpr size_t OFF_HDD = OFF_HE  + (size_t)2 * 2 * B_ * H_ * 2;    // dec h fp16 [2 par][B][HD]
constexpr size_t OFF_CD  = OFF_HDD + (size_t)2 * B_ * HD * 2;        // dec c f32 [B][HD]

using h8 = __attribute__((ext_vector_type(8))) _Float16;
using f4 = __attribute__((ext_vector_type(4))) float;

#define DEV static __device__ __forceinline__

DEV float sigm(float x)  { return __fdividef(1.f, 1.f + __expf(-x)); }
DEV float tanh_(float x) { return 1.f - __fdividef(2.f, __expf(2.f * x) + 1.f); }

// two-level tree barrier: 32 leaf counters (8 blocks each) -> mid counter -> release word
DEV void grid_sync(unsigned* bar, unsigned& phase) {
  __syncthreads();
  if (threadIdx.x == 0) {
    ++phase;
    __threadfence();  // make this block's stores device-visible
    unsigned* leaf = bar + 32 + (blockIdx.x & 31) * 16;
    unsigned a = __hip_atomic_fetch_add(leaf, 1u, __ATOMIC_ACQ_REL, __HIP_MEMORY_SCOPE_AGENT);
    if ((a & 7u) == 7u) {
      unsigned m = __hip_atomic_fetch_add(bar + 16, 1u, __ATOMIC_ACQ_REL, __HIP_MEMORY_SCOPE_AGENT);
      if ((m & 31u) == 31u)
        __hip_atomic_store(bar, phase, __ATOMIC_RELEASE, __HIP_MEMORY_SCOPE_AGENT);
    }
    while (__hip_atomic_load(bar, __ATOMIC_ACQUIRE, __HIP_MEMORY_SCOPE_AGENT) < phase)
      __builtin_amdgcn_s_sleep(1);
    __threadfence();  // invalidate stale cached lines before block proceeds
  }
  __syncthreads();
}

// ---------------- prep kernels ----------------
__global__ void prep_misc(const float* bihF, const float* bhhF,
                          const float* bihB, const float* bhhB,
                          const float* dbih, const float* dbhh,
                          const float* dwih, const float* fcb,
                          float* out, char* ws) {
  int i = blockIdx.x * blockDim.x + threadIdx.x;
  if (i < 1024) ((unsigned*)(ws + OFF_BAR))[i] = 0u;
  if (i < GE) {
    ((float*)(ws + OFF_BF))[i] = bihF[i] + bhhF[i];
    ((float*)(ws + OFF_BB))[i] = bihB[i] + bhhB[i];
  }
  if (i < GD) {
    ((float*)(ws + OFF_BD))[i]  = dbih[i] + dbhh[i];
    ((float*)(ws + OFF_WIH))[i] = dwih[i];
  }
  if (i < B_ * L_) out[i] = fcb[0];
  if (i < 2 * 2 * B_ * H_) ((_Float16*)(ws + OFF_HE))[i] = (_Float16)0.f;
}

__global__ void conv_encw(const float* WihF, const float* WhhF,
                          const float* WihB, const float* WhhB, char* ws) {
  int i = blockIdx.x * blockDim.x + threadIdx.x;
  if (i >= GE * KE) return;
  int r = i / KE, k = i - r * KE;
  float vF = (k < F_) ? WihF[r * F_ + k] : WhhF[r * H_ + (k - F_)];
  float vB = (k < F_) ? WihB[r * F_ + k] : WhhB[r * H_ + (k - F_)];
  ((_Float16*)(ws + OFF_WCF))[i] = (_Float16)vF;
  ((_Float16*)(ws + OFF_WCB))[i] = (_Float16)vB;
}

__global__ void conv_decw(const float* W, char* ws) {
  int i = blockIdx.x * blockDim.x + threadIdx.x;
  if (i < GD * HD) ((_Float16*)(ws + OFF_WD))[i] = (_Float16)W[i];
}

__global__ void conv_x(const float* x, char* ws) {
  int i = blockIdx.x * blockDim.x + threadIdx.x;
  if (i >= T_ * B_ * F_) return;
  int f = i & 127, b = (i >> 7) & 255, t = i >> 15;
  ((_Float16*)(ws + OFF_XH))[i] = (_Float16)x[((size_t)b * T_ + t) * F_ + f];
}

// ---------------- persistent RNN kernel ----------------
__global__ __launch_bounds__(256, 1)
void rnn_kernel(const float* __restrict__ fcW, float* __restrict__ out,
                char* __restrict__ ws) {
  __shared__ __align__(16) _Float16 lds[64 * DPAD];  // 132096 B

  const int tid  = threadIdx.x;
  const int wave = tid >> 6;
  const int lane = tid & 63;
  const int quad = lane >> 4;
  const int col  = lane & 15;
  const int bi   = blockIdx.x;

  unsigned* bar = (unsigned*)(ws + OFF_BAR);
  const _Float16* Wenc  = (const _Float16*)(ws + (bi >= 128 ? OFF_WCB : OFF_WCF));
  const _Float16* Wd    = (const _Float16*)(ws + OFF_WD);
  const float*    biasE = (const float*)(ws + (bi >= 128 ? OFF_BB : OFF_BF));
  const float*    biasD = (const float*)(ws + OFF_BD);
  const float*    wihD  = (const float*)(ws + OFF_WIH);
  const _Float16* Xh    = (const _Float16*)(ws + OFF_XH);
  _Float16* hE = (_Float16*)(ws + OFF_HE);
  _Float16* hD = (_Float16*)(ws + OFF_HDD);
  float*    cD = (float*)(ws + OFF_CD);

  unsigned phase = 0;

  // ================= encoder =================
  {
    const int dir   = bi >> 7;
    const int slice = (bi & 127) >> 2;  // 0..31 -> 16 hidden units
    const int chunk = bi & 3;           // 64 batch rows
    const int j0 = slice * 16;
    const int mb = chunk * 64;

    // stage 64 gate rows x 640 K of combined [Wih|Whh] into LDS; row n = g*16+u
    for (int it = 0; it < 20; ++it) {
      int idx = it * 256 + tid;          // 5120 x 16B
      int n = idx / 80, e = idx - n * 80;
      int g = n >> 4, u = n & 15;
      *((h8*)(lds + n * EPAD) + e) =
          *((const h8*)(Wenc + (size_t)(g * H_ + j0 + u) * KE) + e);
    }
    float breg[4];
#pragma unroll
    for (int g = 0; g < 4; ++g) breg[g] = biasE[g * H_ + j0 + col];
    float cst[4] = {0.f, 0.f, 0.f, 0.f};
    __syncthreads();

    const int arow = mb + wave * 16 + col;       // A-frag batch row
    const int mrow = mb + wave * 16 + quad * 4;  // C-frag batch row base

    for (int t = 0; t < T_; ++t) {
      const int par = t & 1;
      const int tx  = dir ? (T_ - 1 - t) : t;
      f4 z = {0.f, 0.f, 0.f, 0.f};
      f4 acc[4] = {z, z, z, z};

      const h8* xr = (const h8*)(Xh + ((size_t)tx * B_ + arow) * F_);
      const h8* hr = (const h8*)(hE + ((size_t)(par * 2 + dir) * B_ + arow) * H_);

#pragma unroll
      for (int kk = 0; kk < 4; ++kk) {  // x part, K=128
        h8 a = xr[kk * 4 + quad];
#pragma unroll
        for (int g = 0; g < 4; ++g) {
          h8 b = *((const h8*)(lds + (g * 16 + col) * EPAD) + kk * 4 + quad);
          acc[g] = __builtin_amdgcn_mfma_f32_16x16x32_f16(a, b, acc[g], 0, 0, 0);
        }
      }
#pragma unroll
      for (int kk = 0; kk < 16; ++kk) {  // h part, K=512
        h8 a = hr[kk * 4 + quad];
#pragma unroll
        for (int g = 0; g < 4; ++g) {
          h8 b = *((const h8*)(lds + (g * 16 + col) * EPAD + F_) + kk * 4 + quad);
          acc[g] = __builtin_amdgcn_mfma_f32_16x16x32_f16(a, b, acc[g], 0, 0, 0);
        }
      }

      _Float16* ho = hE + ((size_t)((par ^ 1) * 2 + dir) * B_) * H_;
#pragma unroll
      for (int r = 0; r < 4; ++r) {
        float gi = acc[0][r] + breg[0];
        float gf = acc[1][r] + breg[1];
        float gg = acc[2][r] + breg[2];
        float go = acc[3][r] + breg[3];
        float c = sigm(gf) * cst[r] + sigm(gi) * tanh_(gg);
        cst[r] = c;
        float h = sigm(go) * tanh_(c);
        ho[(size_t)(mrow + r) * H_ + j0 + col] = (_Float16)h;
        if (t == T_ - 1) {  // hand off final state to decoder buffers
          hD[(size_t)(mrow + r) * HD + dir * H_ + j0 + col] = (_Float16)h;
          cD[(size_t)(mrow + r) * HD + dir * H_ + j0 + col] = c;
        }
      }
      grid_sync(bar, phase);
    }
  }

  // ================= decoder =================
  {
    const int slice = bi >> 2;  // 0..63 -> 16 hidden units
    const int chunk = bi & 3;
    const int j0 = slice * 16;
    const int mb = chunk * 64;

    for (int it = 0; it < 32; ++it) {  // stage 64 x 1024 dec weight rows
      int idx = it * 256 + tid;
      int n = idx >> 7, e = idx & 127;
      int g = n >> 4, u = n & 15;
      *((h8*)(lds + n * DPAD) + e) =
          *((const h8*)(Wd + (size_t)(g * HD + j0 + u) * HD) + e);
    }
    float breg[4], wreg[4];
#pragma unroll
    for (int g = 0; g < 4; ++g) {
      breg[g] = biasD[g * HD + j0 + col];
      wreg[g] = wihD[g * HD + j0 + col];
    }
    const float fcw = fcW[j0 + col];
    const int arow = mb + wave * 16 + col;
    const int mrow = mb + wave * 16 + quad * 4;
    float cst[4];
#pragma unroll
    for (int r = 0; r < 4; ++r)
      cst[r] = cD[(size_t)(mrow + r) * HD + j0 + col];
    __syncthreads();

    for (int l = 0; l < L_; ++l) {
      const int par = l & 1;
      f4 z = {0.f, 0.f, 0.f, 0.f};
      f4 acc[4] = {z, z, z, z};
      const h8* hr = (const h8*)(hD + ((size_t)par * B_ + arow) * HD);
#pragma unroll
      for (int kk = 0; kk < 32; ++kk) {
        h8 a = hr[kk * 4 + quad];
#pragma unroll
        for (int g = 0; g < 4; ++g) {
          h8 b = *((const h8*)(lds + (g * 16 + col) * DPAD) + kk * 4 + quad);
          acc[g] = __builtin_amdgcn_mfma_f32_16x16x32_f16(a, b, acc[g], 0, 0, 0);
        }
      }
      float pr[4];
#pragma unroll
      for (int r = 0; r < 4; ++r)
        pr[r] = (l > 0) ? out[(size_t)(mrow + r) * L_ + (l - 1)] : 0.f;

      _Float16* ho = hD + (size_t)(par ^ 1) * B_ * HD;
      float sum[4];
#pragma unroll
      for (int r = 0; r < 4; ++r) {
        float gi = acc[0][r] + breg[0] + pr[r] * wreg[0];
        float gf = acc[1][r] + breg[1] + pr[r] * wreg[1];
        float gg = acc[2][r] + breg[2] + pr[r] * wreg[2];
        float go = acc[3][r] + breg[3] + pr[r] * wreg[3];
        float c = sigm(gf) * cst[r] + sigm(gi) * tanh_(gg);
        cst[r] = c;
        float h = sigm(go) * tanh_(c);
        ho[(size_t)(mrow + r) * HD + j0 + col] = (_Float16)h;
        sum[r] = h * fcw;
      }
#pragma unroll
      for (int off = 1; off < 16; off <<= 1) {
#pragma unroll
        for (int r = 0; r < 4; ++r) sum[r] += __shfl_xor(sum[r], off, 16);
      }
      if (col == 0) {
#pragma unroll
        for (int r = 0; r < 4; ++r)
          atomicAdd(&out[(size_t)(mrow + r) * L_ + l], sum[r]);
      }
      grid_sync(bar, phase);
    }
  }
}

extern "C" void kernel_launch(void* const* d_in, const int* in_sizes, int n_in,
                              void* d_out, int out_size, void* d_ws, size_t ws_size,
                              hipStream_t stream) {
  const float* x     = (const float*)d_in[0];
  const float* eWihF = (const float*)d_in[1];
  const float* eWhhF = (const float*)d_in[2];
  const float* ebihF = (const float*)d_in[3];
  const float* ebhhF = (const float*)d_in[4];
  const float* eWihB = (const float*)d_in[5];
  const float* eWhhB = (const float*)d_in[6];
  const float* ebihB = (const float*)d_in[7];
  const float* ebhhB = (const float*)d_in[8];
  const float* dWih  = (const float*)d_in[9];
  const float* dWhh  = (const float*)d_in[10];
  const float* dbih  = (const float*)d_in[11];
  const float* dbhh  = (const float*)d_in[12];
  const float* fcW   = (const float*)d_in[13];
  const float* fcb   = (const float*)d_in[14];
  float* out = (float*)d_out;
  char*  ws  = (char*)d_ws;

  prep_misc<<<2048, 256, 0, stream>>>(ebihF, ebhhF, ebihB, ebhhB, dbih, dbhh,
                                      dWih, fcb, out, ws);
  conv_encw<<<(GE * KE) / 256, 256, 0, stream>>>(eWihF, eWhhF, eWihB, eWhhB, ws);
  conv_decw<<<(GD * HD) / 256, 256, 0, stream>>>(dWhh, ws);
  conv_x<<<(T_ * B_ * F_) / 256, 256, 0, stream>>>(x, ws);

  void* args[] = {(void*)&fcW, (void*)&out, (void*)&ws};
  hipError_t err = hipLaunchCooperativeKernel(rnn_kernel, dim3(256), dim3(256),
                                              args, 0, stream);
  if (err != hipSuccess) {
    // custom barrier doesn't need the CG runtime; 1 block/CU x 256 blocks is
    // always co-resident, so a plain launch is a safe fallback.
    rnn_kernel<<<dim3(256), dim3(256), 0, stream>>>(fcW, out, ws);
  }
}

// Round 3
// 2107.263 us; speedup vs baseline: 3.1437x; 3.1437x over previous
//
#include <hip/hip_runtime.h>

// RNN_M2M: bidirectional LSTM encoder (T=168,B=256,F=128,H=512) + autoregressive
// LSTM decoder (hidden 1024, 48 steps) + scalar FC.
// Persistent kernel, fp16 MFMA 16x16x32. Cross-block h/c/pred exchange goes
// through L3 via cache-bypassing relaxed atomics (no agent fences -> no L2
// writeback/invalidate). Sync = per-domain counters (32 or 64 blocks).
// R3 fix: h-tile store covers all 16 units/row (2 threads x 16B each), was 8.

constexpr int B_ = 256, T_ = 168, F_ = 128, H_ = 512, L_ = 48;
constexpr int KE = F_ + H_;   // 640
constexpr int HD = 1024;
constexpr int GE = 4 * H_;    // 2048
constexpr int GD = 4 * HD;    // 4096
constexpr int EPAD = KE + 8;  // LDS stride (halves)
constexpr int DPAD = HD + 8;

// workspace layout (bytes)
constexpr size_t OFF_BAR = 0;                                        // 4KB counters
constexpr size_t OFF_WCF = 4096;
constexpr size_t OFF_WCB = OFF_WCF + (size_t)GE * KE * 2;
constexpr size_t OFF_WD  = OFF_WCB + (size_t)GE * KE * 2;
constexpr size_t OFF_BF  = OFF_WD  + (size_t)GD * HD * 2;
constexpr size_t OFF_BB  = OFF_BF  + (size_t)GE * 4;
constexpr size_t OFF_BD  = OFF_BB  + (size_t)GE * 4;
constexpr size_t OFF_WIH = OFF_BD  + (size_t)GD * 4;
constexpr size_t OFF_XH  = OFF_WIH + (size_t)GD * 4;
constexpr size_t OFF_HE  = OFF_XH  + (size_t)T_ * B_ * F_ * 2;       // h enc fp16 [2 par][2 dir][B][H]
constexpr size_t OFF_HDD = OFF_HE  + (size_t)2 * 2 * B_ * H_ * 2;    // h dec fp16 [2 par][B][HD]
constexpr size_t OFF_CD  = OFF_HDD + (size_t)2 * B_ * HD * 2;        // c dec f32 [B][HD]

using h8 = __attribute__((ext_vector_type(8))) _Float16;
using f4 = __attribute__((ext_vector_type(4))) float;

#define DEV static __device__ __forceinline__

DEV float sigm(float x)  { return __fdividef(1.f, 1.f + __expf(-x)); }
DEV float tanh_(float x) { return 1.f - __fdividef(2.f, __expf(2.f * x) + 1.f); }

// ---- cache-bypassing (L3-coherent) accessors: relaxed atomics, no fences ----
DEV unsigned long long aload_u64(const void* p) {
  return __hip_atomic_load((const unsigned long long*)p, __ATOMIC_RELAXED,
                           __HIP_MEMORY_SCOPE_AGENT);
}
DEV void astore_u64(void* p, unsigned long long v) {
  __hip_atomic_store((unsigned long long*)p, v, __ATOMIC_RELAXED,
                     __HIP_MEMORY_SCOPE_AGENT);
}
DEV float aload_f32(const void* p) {
  return __hip_atomic_load((const float*)p, __ATOMIC_RELAXED,
                           __HIP_MEMORY_SCOPE_AGENT);
}
DEV void astore_f32(void* p, float v) {
  __hip_atomic_store((float*)p, v, __ATOMIC_RELAXED, __HIP_MEMORY_SCOPE_AGENT);
}
DEV h8 aload_h8(const void* p) {
  union { unsigned long long q[2]; h8 v; } u;
  u.q[0] = aload_u64(p);
  u.q[1] = aload_u64((const char*)p + 8);
  return u.v;
}
DEV void vm_drain() { asm volatile("s_waitcnt vmcnt(0)" ::: "memory"); }

// per-domain sync: every wave drains its bypass stores to L3, then one lane
// bumps the domain counter and polls to the monotone target. No cache ops.
DEV void domain_sync(unsigned* cnt, unsigned target) {
  vm_drain();
  __syncthreads();
  if (threadIdx.x == 0) {
    __hip_atomic_fetch_add(cnt, 1u, __ATOMIC_RELAXED, __HIP_MEMORY_SCOPE_AGENT);
    while (__hip_atomic_load(cnt, __ATOMIC_RELAXED, __HIP_MEMORY_SCOPE_AGENT) < target)
      __builtin_amdgcn_s_sleep(1);
  }
  __syncthreads();
  asm volatile("" ::: "memory");
}

// ---------------- prep kernels ----------------
__global__ void prep_misc(const float* bihF, const float* bhhF,
                          const float* bihB, const float* bhhB,
                          const float* dbih, const float* dbhh,
                          const float* dwih, const float* fcb,
                          float* out, char* ws) {
  int i = blockIdx.x * blockDim.x + threadIdx.x;
  if (i < 1024) ((unsigned*)(ws + OFF_BAR))[i] = 0u;
  if (i < GE) {
    ((float*)(ws + OFF_BF))[i] = bihF[i] + bhhF[i];
    ((float*)(ws + OFF_BB))[i] = bihB[i] + bhhB[i];
  }
  if (i < GD) {
    ((float*)(ws + OFF_BD))[i]  = dbih[i] + dbhh[i];
    ((float*)(ws + OFF_WIH))[i] = dwih[i];
  }
  if (i < B_ * L_) out[i] = fcb[0];
  // zero h buffers THROUGH the bypass path so rnn's bypass reads see them
  if (i < 2 * 2 * B_ * H_ / 4) astore_u64((char*)ws + OFF_HE + (size_t)i * 8, 0ull);
}

__global__ void conv_encw(const float* WihF, const float* WhhF,
                          const float* WihB, const float* WhhB, char* ws) {
  int i = blockIdx.x * blockDim.x + threadIdx.x;
  if (i >= GE * KE) return;
  int r = i / KE, k = i - r * KE;
  float vF = (k < F_) ? WihF[r * F_ + k] : WhhF[r * H_ + (k - F_)];
  float vB = (k < F_) ? WihB[r * F_ + k] : WhhB[r * H_ + (k - F_)];
  ((_Float16*)(ws + OFF_WCF))[i] = (_Float16)vF;
  ((_Float16*)(ws + OFF_WCB))[i] = (_Float16)vB;
}

__global__ void conv_decw(const float* W, char* ws) {
  int i = blockIdx.x * blockDim.x + threadIdx.x;
  if (i < GD * HD) ((_Float16*)(ws + OFF_WD))[i] = (_Float16)W[i];
}

__global__ void conv_x(const float* x, char* ws) {
  int i = blockIdx.x * blockDim.x + threadIdx.x;
  if (i >= T_ * B_ * F_) return;
  int f = i & 127, b = (i >> 7) & 255, t = i >> 15;
  ((_Float16*)(ws + OFF_XH))[i] = (_Float16)x[((size_t)b * T_ + t) * F_ + f];
}

// ---------------- persistent RNN kernel ----------------
__global__ __launch_bounds__(256, 1)
void rnn_kernel(const float* __restrict__ fcW, float* __restrict__ out,
                char* __restrict__ ws) {
  __shared__ __align__(16) _Float16 lds[64 * DPAD];   // 132096 B (weights)
  __shared__ __align__(16) _Float16 htile[64][16];    // 2 KB h transpose tile

  const int tid  = threadIdx.x;
  const int wave = tid >> 6;
  const int lane = tid & 63;
  const int quad = lane >> 4;
  const int col  = lane & 15;
  const int bi   = blockIdx.x;

  unsigned* bar = (unsigned*)(ws + OFF_BAR);  // counters spaced 128B
  const _Float16* Wenc  = (const _Float16*)(ws + (bi >= 128 ? OFF_WCB : OFF_WCF));
  const _Float16* Wd    = (const _Float16*)(ws + OFF_WD);
  const float*    biasE = (const float*)(ws + (bi >= 128 ? OFF_BB : OFF_BF));
  const float*    biasD = (const float*)(ws + OFF_BD);
  const float*    wihD  = (const float*)(ws + OFF_WIH);
  const _Float16* Xh    = (const _Float16*)(ws + OFF_XH);
  _Float16* hE = (_Float16*)(ws + OFF_HE);
  _Float16* hD = (_Float16*)(ws + OFF_HDD);
  float*    cD = (float*)(ws + OFF_CD);

  // ================= encoder =================
  const int dir   = bi >> 7;
  const int chunk = bi & 3;
  {
    const int slice = (bi & 127) >> 2;  // 0..31 -> 16 hidden units
    const int j0 = slice * 16;
    const int mb = chunk * 64;
    unsigned* ecnt = bar + (dir * 4 + chunk) * 32;

    for (int it = 0; it < 20; ++it) {   // stage 64 gate rows x 640 K
      int idx = it * 256 + tid;
      int n = idx / 80, e = idx - n * 80;
      int g = n >> 4, u = n & 15;
      *((h8*)(lds + n * EPAD) + e) =
          *((const h8*)(Wenc + (size_t)(g * H_ + j0 + u) * KE) + e);
    }
    float breg[4];
#pragma unroll
    for (int g = 0; g < 4; ++g) breg[g] = biasE[g * H_ + j0 + col];
    float cst[4] = {0.f, 0.f, 0.f, 0.f};
    __syncthreads();

    const int arow = mb + wave * 16 + col;
    const int mrow = mb + wave * 16 + quad * 4;

    for (int t = 0; t < T_; ++t) {
      const int par = t & 1;
      const int tx  = dir ? (T_ - 1 - t) : t;
      f4 z = {0.f, 0.f, 0.f, 0.f};
      f4 acc[4] = {z, z, z, z};

      const h8* xr = (const h8*)(Xh + ((size_t)tx * B_ + arow) * F_);
      const h8* hr = (const h8*)(hE + ((size_t)(par * 2 + dir) * B_ + arow) * H_);

#pragma unroll
      for (int kk = 0; kk < 4; ++kk) {  // x part K=128 (cached reads)
        h8 a = xr[kk * 4 + quad];
#pragma unroll
        for (int g = 0; g < 4; ++g) {
          h8 b = *((const h8*)(lds + (g * 16 + col) * EPAD) + kk * 4 + quad);
          acc[g] = __builtin_amdgcn_mfma_f32_16x16x32_f16(a, b, acc[g], 0, 0, 0);
        }
      }
#pragma unroll
      for (int kk = 0; kk < 16; ++kk) { // h part K=512 (bypass reads)
        h8 a = aload_h8((const h8*)hr + kk * 4 + quad);
#pragma unroll
        for (int g = 0; g < 4; ++g) {
          h8 b = *((const h8*)(lds + (g * 16 + col) * EPAD + F_) + kk * 4 + quad);
          acc[g] = __builtin_amdgcn_mfma_f32_16x16x32_f16(a, b, acc[g], 0, 0, 0);
        }
      }

#pragma unroll
      for (int r = 0; r < 4; ++r) {
        float gi = acc[0][r] + breg[0];
        float gf = acc[1][r] + breg[1];
        float gg = acc[2][r] + breg[2];
        float go = acc[3][r] + breg[3];
        float c = sigm(gf) * cst[r] + sigm(gi) * tanh_(gg);
        cst[r] = c;
        float h = sigm(go) * tanh_(c);
        htile[wave * 16 + quad * 4 + r][col] = (_Float16)h;
        if (t == T_ - 1)
          astore_f32(&cD[(size_t)(mrow + r) * HD + dir * H_ + j0 + col], c);
      }
      __syncthreads();  // tile complete
      if (tid < 128) {  // 64 rows x 32B/row; 2 threads/row x 16B (two u64 each)
        int row = tid >> 1, half = tid & 1;
        const unsigned long long* src =
            (const unsigned long long*)&htile[row][half * 8];
        _Float16* dst;
        if (t < T_ - 1)
          dst = hE + ((size_t)((par ^ 1) * 2 + dir) * B_ + mb + row) * H_ +
                j0 + half * 8;
        else
          dst = hD + (size_t)(mb + row) * HD + dir * H_ + j0 + half * 8;
        astore_u64(dst, src[0]);
        astore_u64(dst + 4, src[1]);
      }
      if (t < T_ - 1) domain_sync(ecnt, 32u * (t + 1));
    }
  }

  // ============ encoder->decoder handoff (64 blocks of this chunk) ============
  domain_sync(bar + (8 + chunk) * 32, 64u);

  // ================= decoder =================
  {
    const int slice = bi >> 2;  // 0..63
    const int j0 = slice * 16;
    const int mb = chunk * 64;
    unsigned* dcnt = bar + (12 + chunk) * 32;

    for (int it = 0; it < 32; ++it) {  // stage 64 x 1024 dec weight rows
      int idx = it * 256 + tid;
      int n = idx >> 7, e = idx & 127;
      int g = n >> 4, u = n & 15;
      *((h8*)(lds + n * DPAD) + e) =
          *((const h8*)(Wd + (size_t)(g * HD + j0 + u) * HD) + e);
    }
    float breg[4], wreg[4];
#pragma unroll
    for (int g = 0; g < 4; ++g) {
      breg[g] = biasD[g * HD + j0 + col];
      wreg[g] = wihD[g * HD + j0 + col];
    }
    const float fcw = fcW[j0 + col];
    const int arow = mb + wave * 16 + col;
    const int mrow = mb + wave * 16 + quad * 4;
    float cst[4];
#pragma unroll
    for (int r = 0; r < 4; ++r)
      cst[r] = aload_f32(&cD[(size_t)(mrow + r) * HD + j0 + col]);
    __syncthreads();

    for (int l = 0; l < L_; ++l) {
      const int par = l & 1;
      f4 z = {0.f, 0.f, 0.f, 0.f};
      f4 acc[4] = {z, z, z, z};
      const h8* hr = (const h8*)(hD + ((size_t)par * B_ + arow) * HD);
#pragma unroll
      for (int kk = 0; kk < 32; ++kk) {
        h8 a = aload_h8((const h8*)hr + kk * 4 + quad);
#pragma unroll
        for (int g = 0; g < 4; ++g) {
          h8 b = *((const h8*)(lds + (g * 16 + col) * DPAD) + kk * 4 + quad);
          acc[g] = __builtin_amdgcn_mfma_f32_16x16x32_f16(a, b, acc[g], 0, 0, 0);
        }
      }
      float pr[4];
#pragma unroll
      for (int r = 0; r < 4; ++r)
        pr[r] = (l > 0) ? aload_f32(&out[(size_t)(mrow + r) * L_ + (l - 1)]) : 0.f;

      float sum[4];
#pragma unroll
      for (int r = 0; r < 4; ++r) {
        float gi = acc[0][r] + breg[0] + pr[r] * wreg[0];
        float gf = acc[1][r] + breg[1] + pr[r] * wreg[1];
        float gg = acc[2][r] + breg[2] + pr[r] * wreg[2];
        float go = acc[3][r] + breg[3] + pr[r] * wreg[3];
        float c = sigm(gf) * cst[r] + sigm(gi) * tanh_(gg);
        cst[r] = c;
        float h = sigm(go) * tanh_(c);
        htile[wave * 16 + quad * 4 + r][col] = (_Float16)h;
        sum[r] = h * fcw;
      }
#pragma unroll
      for (int off = 1; off < 16; off <<= 1) {
#pragma unroll
        for (int r = 0; r < 4; ++r) sum[r] += __shfl_xor(sum[r], off, 16);
      }
      if (col == 0) {
#pragma unroll
        for (int r = 0; r < 4; ++r)
          atomicAdd(&out[(size_t)(mrow + r) * L_ + l], sum[r]);
      }
      __syncthreads();  // tile complete
      if (l < L_ - 1) {
        if (tid < 128) {
          int row = tid >> 1, half = tid & 1;
          const unsigned long long* src =
              (const unsigned long long*)&htile[row][half * 8];
          _Float16* dst = hD + ((size_t)(par ^ 1) * B_ + mb + row) * HD +
                          j0 + half * 8;
          astore_u64(dst, src[0]);
          astore_u64(dst + 4, src[1]);
        }
        domain_sync(dcnt, 64u * (l + 1));
      }
    }
  }
}

extern "C" void kernel_launch(void* const* d_in, const int* in_sizes, int n_in,
                              void* d_out, int out_size, void* d_ws, size_t ws_size,
                              hipStream_t stream) {
  const float* x     = (const float*)d_in[0];
  const float* eWihF = (const float*)d_in[1];
  const float* eWhhF = (const float*)d_in[2];
  const float* ebihF = (const float*)d_in[3];
  const float* ebhhF = (const float*)d_in[4];
  const float* eWihB = (const float*)d_in[5];
  const float* eWhhB = (const float*)d_in[6];
  const float* ebihB = (const float*)d_in[7];
  const float* ebhhB = (const float*)d_in[8];
  const float* dWih  = (const float*)d_in[9];
  const float* dWhh  = (const float*)d_in[10];
  const float* dbih  = (const float*)d_in[11];
  const float* dbhh  = (const float*)d_in[12];
  const float* fcW   = (const float*)d_in[13];
  const float* fcb   = (const float*)d_in[14];
  float* out = (float*)d_out;
  char*  ws  = (char*)d_ws;

  prep_misc<<<2048, 256, 0, stream>>>(ebihF, ebhhF, ebihB, ebhhB, dbih, dbhh,
                                      dWih, fcb, out, ws);
  conv_encw<<<(GE * KE) / 256, 256, 0, stream>>>(eWihF, eWhhF, eWihB, eWhhB, ws);
  conv_decw<<<(GD * HD) / 256, 256, 0, stream>>>(dWhh, ws);
  conv_x<<<(T_ * B_ * F_) / 256, 256, 0, stream>>>(x, ws);

  void* args[] = {(void*)&fcW, (void*)&out, (void*)&ws};
  hipError_t err = hipLaunchCooperativeKernel(rnn_kernel, dim3(256), dim3(256),
                                              args, 0, stream);
  if (err != hipSuccess) {
    // 256 blocks x 1 block/CU on 256 CUs are co-resident under plain launch too
    rnn_kernel<<<dim3(256), dim3(256), 0, stream>>>(fcW, out, ws);
  }
}

// Round 5
// 1502.561 us; speedup vs baseline: 4.4089x; 1.4024x over previous
//
#include <hip/hip_runtime.h>

// RNN_M2M: bidirectional LSTM encoder (T=168,B=256,F=128,H=512) + autoregressive
// LSTM decoder (hidden 1024, 48 steps) + scalar FC.
// R5 = R4 design + earlyclobber ("=&v") on all inline-asm load outputs (R4's
// coredump: outputs could alias the address pair; early-returning loads
// clobbered the address mid-sequence).
// Encoder h-exchange is XCD-local: blocks read physical XCC_ID, claim a
// per-XCD rank; domain = XCD (32 blocks = 32 CUs at 1 block/CU). Producers
// plain-store h into the shared XCD L2; consumers use sc0 (L1-bypass) loads;
// sync is a store-only flag line. Decoder stays agent/L3-scope (domains span
// XCDs) with flag-line sync + batched asm h-loads.

constexpr int B_ = 256, T_ = 168, F_ = 128, H_ = 512, L_ = 48;
constexpr int KE = F_ + H_;   // 640
constexpr int HD = 1024;
constexpr int GE = 4 * H_;    // 2048
constexpr int GD = 4 * HD;    // 4096
constexpr int EPAD = KE + 8;  // LDS stride (halves)
constexpr int DPAD = HD + 8;

// sync area (u32 indices into ws): 8 KB total
constexpr int GBAR_IDX = 0;     // global barrier counter (line 0)
constexpr int CLAIM_IDX = 64;   // claim[k] at CLAIM_IDX + k*64, k=0..7
constexpr int ENCF_IDX = 640;   // enc flags: + d*64 + s   (d=0..7, s=0..31)
constexpr int DECF_IDX = 1280;  // dec flags: + c*64 + s   (c=0..3, s=0..63)

// workspace layout (bytes)
constexpr size_t OFF_SYNC = 0;                                       // 8KB
constexpr size_t OFF_WCF = 8192;
constexpr size_t OFF_WCB = OFF_WCF + (size_t)GE * KE * 2;
constexpr size_t OFF_WD  = OFF_WCB + (size_t)GE * KE * 2;
constexpr size_t OFF_BF  = OFF_WD  + (size_t)GD * HD * 2;
constexpr size_t OFF_BB  = OFF_BF  + (size_t)GE * 4;
constexpr size_t OFF_BD  = OFF_BB  + (size_t)GE * 4;
constexpr size_t OFF_WIH = OFF_BD  + (size_t)GD * 4;
constexpr size_t OFF_XH  = OFF_WIH + (size_t)GD * 4;
constexpr size_t OFF_HE  = OFF_XH  + (size_t)T_ * B_ * F_ * 2;       // h enc fp16 [2 par][2 dir][B][H]
constexpr size_t OFF_HDD = OFF_HE  + (size_t)2 * 2 * B_ * H_ * 2;    // h dec fp16 [2 par][B][HD]
constexpr size_t OFF_CD  = OFF_HDD + (size_t)2 * B_ * HD * 2;        // c dec f32 [B][HD]

using h8 = __attribute__((ext_vector_type(8))) _Float16;
using f4 = __attribute__((ext_vector_type(4))) float;

#define DEV static __device__ __forceinline__

DEV float sigm(float x)  { return __fdividef(1.f, 1.f + __expf(-x)); }
DEV float tanh_(float x) { return 1.f - __fdividef(2.f, __expf(2.f * x) + 1.f); }

DEV h8 as_h8(f4 v) { union { f4 f; h8 h; } u; u.f = v; return u.h; }

// ---- agent-scope (L3-coherent) accessors ----
DEV void astore_u64(void* p, unsigned long long v) {
  __hip_atomic_store((unsigned long long*)p, v, __ATOMIC_RELAXED,
                     __HIP_MEMORY_SCOPE_AGENT);
}
DEV void astore_u32(void* p, unsigned v) {
  __hip_atomic_store((unsigned*)p, v, __ATOMIC_RELAXED, __HIP_MEMORY_SCOPE_AGENT);
}
DEV unsigned aload_u32(const void* p) {
  return __hip_atomic_load((const unsigned*)p, __ATOMIC_RELAXED,
                           __HIP_MEMORY_SCOPE_AGENT);
}
DEV float aload_f32(const void* p) {
  return __hip_atomic_load((const float*)p, __ATOMIC_RELAXED,
                           __HIP_MEMORY_SCOPE_AGENT);
}
DEV void astore_f32(void* p, float v) {
  __hip_atomic_store((float*)p, v, __ATOMIC_RELAXED, __HIP_MEMORY_SCOPE_AGENT);
}
DEV void vm_drain() { asm volatile("s_waitcnt vmcnt(0)" ::: "memory"); }

// ---- batched h loads: one asm block, single waitcnt ----
// NOTE "=&v" earlyclobber: outputs must NOT alias the address pair (%16/%32);
// without it, early-returning load data clobbers the address mid-sequence.
template<bool DEEP>
DEV void ld16(const _Float16* p, f4* A) {
#define L16(FL) asm volatile( \
    "global_load_dwordx4 %0,  %16, off" FL "\n\t" \
    "global_load_dwordx4 %1,  %16, off offset:64" FL "\n\t" \
    "global_load_dwordx4 %2,  %16, off offset:128" FL "\n\t" \
    "global_load_dwordx4 %3,  %16, off offset:192" FL "\n\t" \
    "global_load_dwordx4 %4,  %16, off offset:256" FL "\n\t" \
    "global_load_dwordx4 %5,  %16, off offset:320" FL "\n\t" \
    "global_load_dwordx4 %6,  %16, off offset:384" FL "\n\t" \
    "global_load_dwordx4 %7,  %16, off offset:448" FL "\n\t" \
    "global_load_dwordx4 %8,  %16, off offset:512" FL "\n\t" \
    "global_load_dwordx4 %9,  %16, off offset:576" FL "\n\t" \
    "global_load_dwordx4 %10, %16, off offset:640" FL "\n\t" \
    "global_load_dwordx4 %11, %16, off offset:704" FL "\n\t" \
    "global_load_dwordx4 %12, %16, off offset:768" FL "\n\t" \
    "global_load_dwordx4 %13, %16, off offset:832" FL "\n\t" \
    "global_load_dwordx4 %14, %16, off offset:896" FL "\n\t" \
    "global_load_dwordx4 %15, %16, off offset:960" FL "\n\t" \
    "s_waitcnt vmcnt(0)" \
    : "=&v"(A[0]),"=&v"(A[1]),"=&v"(A[2]),"=&v"(A[3]),"=&v"(A[4]),"=&v"(A[5]), \
      "=&v"(A[6]),"=&v"(A[7]),"=&v"(A[8]),"=&v"(A[9]),"=&v"(A[10]),"=&v"(A[11]), \
      "=&v"(A[12]),"=&v"(A[13]),"=&v"(A[14]),"=&v"(A[15]) \
    : "v"(p) : "memory")
  if constexpr (DEEP) { L16(" sc0 sc1"); } else { L16(" sc0"); }
#undef L16
}

DEV void ld32(const _Float16* p, f4* A) {
  asm volatile(
    "global_load_dwordx4 %0,  %32, off sc0 sc1\n\t"
    "global_load_dwordx4 %1,  %32, off offset:64 sc0 sc1\n\t"
    "global_load_dwordx4 %2,  %32, off offset:128 sc0 sc1\n\t"
    "global_load_dwordx4 %3,  %32, off offset:192 sc0 sc1\n\t"
    "global_load_dwordx4 %4,  %32, off offset:256 sc0 sc1\n\t"
    "global_load_dwordx4 %5,  %32, off offset:320 sc0 sc1\n\t"
    "global_load_dwordx4 %6,  %32, off offset:384 sc0 sc1\n\t"
    "global_load_dwordx4 %7,  %32, off offset:448 sc0 sc1\n\t"
    "global_load_dwordx4 %8,  %32, off offset:512 sc0 sc1\n\t"
    "global_load_dwordx4 %9,  %32, off offset:576 sc0 sc1\n\t"
    "global_load_dwordx4 %10, %32, off offset:640 sc0 sc1\n\t"
    "global_load_dwordx4 %11, %32, off offset:704 sc0 sc1\n\t"
    "global_load_dwordx4 %12, %32, off offset:768 sc0 sc1\n\t"
    "global_load_dwordx4 %13, %32, off offset:832 sc0 sc1\n\t"
    "global_load_dwordx4 %14, %32, off offset:896 sc0 sc1\n\t"
    "global_load_dwordx4 %15, %32, off offset:960 sc0 sc1\n\t"
    "global_load_dwordx4 %16, %32, off offset:1024 sc0 sc1\n\t"
    "global_load_dwordx4 %17, %32, off offset:1088 sc0 sc1\n\t"
    "global_load_dwordx4 %18, %32, off offset:1152 sc0 sc1\n\t"
    "global_load_dwordx4 %19, %32, off offset:1216 sc0 sc1\n\t"
    "global_load_dwordx4 %20, %32, off offset:1280 sc0 sc1\n\t"
    "global_load_dwordx4 %21, %32, off offset:1344 sc0 sc1\n\t"
    "global_load_dwordx4 %22, %32, off offset:1408 sc0 sc1\n\t"
    "global_load_dwordx4 %23, %32, off offset:1472 sc0 sc1\n\t"
    "global_load_dwordx4 %24, %32, off offset:1536 sc0 sc1\n\t"
    "global_load_dwordx4 %25, %32, off offset:1600 sc0 sc1\n\t"
    "global_load_dwordx4 %26, %32, off offset:1664 sc0 sc1\n\t"
    "global_load_dwordx4 %27, %32, off offset:1728 sc0 sc1\n\t"
    "global_load_dwordx4 %28, %32, off offset:1792 sc0 sc1\n\t"
    "global_load_dwordx4 %29, %32, off offset:1856 sc0 sc1\n\t"
    "global_load_dwordx4 %30, %32, off offset:1920 sc0 sc1\n\t"
    "global_load_dwordx4 %31, %32, off offset:1984 sc0 sc1\n\t"
    "s_waitcnt vmcnt(0)"
    : "=&v"(A[0]),"=&v"(A[1]),"=&v"(A[2]),"=&v"(A[3]),"=&v"(A[4]),"=&v"(A[5]),
      "=&v"(A[6]),"=&v"(A[7]),"=&v"(A[8]),"=&v"(A[9]),"=&v"(A[10]),"=&v"(A[11]),
      "=&v"(A[12]),"=&v"(A[13]),"=&v"(A[14]),"=&v"(A[15]),"=&v"(A[16]),"=&v"(A[17]),
      "=&v"(A[18]),"=&v"(A[19]),"=&v"(A[20]),"=&v"(A[21]),"=&v"(A[22]),"=&v"(A[23]),
      "=&v"(A[24]),"=&v"(A[25]),"=&v"(A[26]),"=&v"(A[27]),"=&v"(A[28]),"=&v"(A[29]),
      "=&v"(A[30]),"=&v"(A[31])
    : "v"(p) : "memory");
}

// flag poll: bounded, lane-parallel, ballot-complete
DEV unsigned pollflag(const unsigned* p, bool deep) {
  unsigned v;
  if (deep)
    asm volatile("global_load_dword %0, %1, off sc0 sc1\n\t"
                 "s_waitcnt vmcnt(0)" : "=&v"(v) : "v"(p) : "memory");
  else
    asm volatile("global_load_dword %0, %1, off sc0\n\t"
                 "s_waitcnt vmcnt(0)" : "=&v"(v) : "v"(p) : "memory");
  return v;
}
DEV void wait_ge(const unsigned* p, unsigned target, bool deep, int cap) {
  for (int it = 0; it < cap; ++it) {
    unsigned v = pollflag(p, deep);
    if (__ballot(v >= target) == ~0ull) return;
    __builtin_amdgcn_s_sleep(2);
  }
}

// global barrier (agent scope, monotone target); bounded
DEV void global_sync(unsigned* cnt, unsigned target) {
  vm_drain();
  __syncthreads();
  if (threadIdx.x == 0) {
    __hip_atomic_fetch_add(cnt, 1u, __ATOMIC_RELAXED, __HIP_MEMORY_SCOPE_AGENT);
    for (int it = 0; it < (1 << 18); ++it) {
      if (aload_u32(cnt) >= target) break;
      __builtin_amdgcn_s_sleep(2);
    }
  }
  __syncthreads();
  asm volatile("" ::: "memory");
}

// ---------------- prep kernels ----------------
__global__ void prep_misc(const float* bihF, const float* bhhF,
                          const float* bihB, const float* bhhB,
                          const float* dbih, const float* dbhh,
                          const float* dwih, const float* fcb,
                          float* out, char* ws) {
  int i = blockIdx.x * blockDim.x + threadIdx.x;
  if (i < 1024) astore_u64(ws + (size_t)i * 8, 0ull);  // 8KB sync area
  if (i < GE) {
    ((float*)(ws + OFF_BF))[i] = bihF[i] + bhhF[i];
    ((float*)(ws + OFF_BB))[i] = bihB[i] + bhhB[i];
  }
  if (i < GD) {
    ((float*)(ws + OFF_BD))[i]  = dbih[i] + dbhh[i];
    ((float*)(ws + OFF_WIH))[i] = dwih[i];
  }
  if (i < B_ * L_) out[i] = fcb[0];
  // zero h buffers through L3 so cold L2/L3 reads see them
  if (i < 2 * 2 * B_ * H_ / 4) astore_u64((char*)ws + OFF_HE + (size_t)i * 8, 0ull);
}

__global__ void conv_encw(const float* WihF, const float* WhhF,
                          const float* WihB, const float* WhhB, char* ws) {
  int i = blockIdx.x * blockDim.x + threadIdx.x;
  if (i >= GE * KE) return;
  int r = i / KE, k = i - r * KE;
  float vF = (k < F_) ? WihF[r * F_ + k] : WhhF[r * H_ + (k - F_)];
  float vB = (k < F_) ? WihB[r * F_ + k] : WhhB[r * H_ + (k - F_)];
  ((_Float16*)(ws + OFF_WCF))[i] = (_Float16)vF;
  ((_Float16*)(ws + OFF_WCB))[i] = (_Float16)vB;
}

__global__ void conv_decw(const float* W, char* ws) {
  int i = blockIdx.x * blockDim.x + threadIdx.x;
  if (i < GD * HD) ((_Float16*)(ws + OFF_WD))[i] = (_Float16)W[i];
}

__global__ void conv_x(const float* x, char* ws) {
  int i = blockIdx.x * blockDim.x + threadIdx.x;
  if (i >= T_ * B_ * F_) return;
  int f = i & 127, b = (i >> 7) & 255, t = i >> 15;
  ((_Float16*)(ws + OFF_XH))[i] = (_Float16)x[((size_t)b * T_ + t) * F_ + f];
}

// ---------------- encoder phase ----------------
template<bool LOCAL>
DEV void encoder_phase(int dir, int chunk, int slice,
                       int tid, int wave, int quad, int col, int lane,
                       char* ws, _Float16* lds, _Float16 (*htile)[16]) {
  const _Float16* Wenc  = (const _Float16*)(ws + (dir ? OFF_WCB : OFF_WCF));
  const float*    biasE = (const float*)(ws + (dir ? OFF_BB : OFF_BF));
  const _Float16* Xh    = (const _Float16*)(ws + OFF_XH);
  _Float16* hE = (_Float16*)(ws + OFF_HE);
  _Float16* hD = (_Float16*)(ws + OFF_HDD);
  float*    cD = (float*)(ws + OFF_CD);
  unsigned* encf = (unsigned*)ws + ENCF_IDX + (dir * 4 + chunk) * 64;

  const int j0 = slice * 16;
  const int mb = chunk * 64;

  for (int it = 0; it < 20; ++it) {   // stage 64 gate rows x 640 K into LDS
    int idx = it * 256 + tid;
    int n = idx / 80, e = idx - n * 80;
    int g = n >> 4, u = n & 15;
    *((h8*)(lds + n * EPAD) + e) =
        *((const h8*)(Wenc + (size_t)(g * H_ + j0 + u) * KE) + e);
  }
  float breg[4];
#pragma unroll
  for (int g = 0; g < 4; ++g) breg[g] = biasE[g * H_ + j0 + col];
  float cst[4] = {0.f, 0.f, 0.f, 0.f};
  __syncthreads();

  const int arow = mb + wave * 16 + col;
  const int mrow = mb + wave * 16 + quad * 4;

  for (int t = 0; t < T_; ++t) {
    const int par = t & 1;
    const int tx  = dir ? (T_ - 1 - t) : t;
    f4 z = {0.f, 0.f, 0.f, 0.f};
    f4 acc[4] = {z, z, z, z};

    // x part (K=128, cached reads) — useful work while peers finish h
    const h8* xr = (const h8*)(Xh + ((size_t)tx * B_ + arow) * F_);
#pragma unroll
    for (int kk = 0; kk < 4; ++kk) {
      h8 a = xr[kk * 4 + quad];
#pragma unroll
      for (int g = 0; g < 4; ++g) {
        h8 b = *((const h8*)(lds + (g * 16 + col) * EPAD) + kk * 4 + quad);
        acc[g] = __builtin_amdgcn_mfma_f32_16x16x32_f16(a, b, acc[g], 0, 0, 0);
      }
    }
    // wait for peers' h of this step
    if (t > 0)
      wait_ge(encf + (lane & 31), (unsigned)t, !LOCAL, LOCAL ? (1 << 14) : (1 << 16));
    // h part (K=512): batched loads, L2-local (sc0) or L3 (sc0 sc1)
    f4 A[16];
    ld16<!LOCAL>(hE + ((size_t)(par * 2 + dir) * B_ + arow) * H_ + quad * 8, A);
#pragma unroll
    for (int kk = 0; kk < 16; ++kk) {
      h8 a = as_h8(A[kk]);
#pragma unroll
      for (int g = 0; g < 4; ++g) {
        h8 b = *((const h8*)(lds + (g * 16 + col) * EPAD + F_) + kk * 4 + quad);
        acc[g] = __builtin_amdgcn_mfma_f32_16x16x32_f16(a, b, acc[g], 0, 0, 0);
      }
    }

#pragma unroll
    for (int r = 0; r < 4; ++r) {
      float gi = acc[0][r] + breg[0];
      float gf = acc[1][r] + breg[1];
      float gg = acc[2][r] + breg[2];
      float go = acc[3][r] + breg[3];
      float c = sigm(gf) * cst[r] + sigm(gi) * tanh_(gg);
      cst[r] = c;
      float h = sigm(go) * tanh_(c);
      htile[wave * 16 + quad * 4 + r][col] = (_Float16)h;
      if (t == T_ - 1)
        astore_f32(&cD[(size_t)(mrow + r) * HD + dir * H_ + j0 + col], c);
    }
    __syncthreads();  // htile complete
    if (tid < 128) {  // 64 rows x 32B/row; 2 threads/row x 16B
      int row = tid >> 1, half = tid & 1;
      const unsigned long long* src =
          (const unsigned long long*)&htile[row][half * 8];
      if (t < T_ - 1) {
        _Float16* dst = hE + ((size_t)((par ^ 1) * 2 + dir) * B_ + mb + row) * H_ +
                        j0 + half * 8;
        if (LOCAL) {  // plain stores -> shared XCD L2 (L1 is write-through)
          ((unsigned long long*)dst)[0] = src[0];
          ((unsigned long long*)(dst + 4))[0] = src[1];
        } else {
          astore_u64(dst, src[0]);
          astore_u64(dst + 4, src[1]);
        }
      } else {        // final h -> decoder buffer, must cross XCDs
        _Float16* dst = hD + (size_t)(mb + row) * HD + dir * H_ + j0 + half * 8;
        astore_u64(dst, src[0]);
        astore_u64(dst + 4, src[1]);
      }
    }
    vm_drain();       // all waves: h (and cD) stores complete
    __syncthreads();  // htile consumed + all drains done
    if (tid == 0 && t < T_ - 1) {
      if (LOCAL) *(volatile unsigned*)(encf + slice) = (unsigned)(t + 1);
      else       astore_u32(encf + slice, (unsigned)(t + 1));
    }
  }
}

// ---------------- decoder phase (agent/L3 scope) ----------------
DEV void decoder_phase(int slice, int chunk,
                       int tid, int wave, int quad, int col, int lane,
                       const float* fcW, float* out, char* ws,
                       _Float16* lds, _Float16 (*htile)[16]) {
  const _Float16* Wd    = (const _Float16*)(ws + OFF_WD);
  const float*    biasD = (const float*)(ws + OFF_BD);
  const float*    wihD  = (const float*)(ws + OFF_WIH);
  _Float16* hD = (_Float16*)(ws + OFF_HDD);
  float*    cD = (float*)(ws + OFF_CD);
  unsigned* decf = (unsigned*)ws + DECF_IDX + chunk * 64;

  const int j0 = slice * 16;
  const int mb = chunk * 64;

  for (int it = 0; it < 32; ++it) {  // stage 64 x 1024 dec weight rows
    int idx = it * 256 + tid;
    int n = idx >> 7, e = idx & 127;
    int g = n >> 4, u = n & 15;
    *((h8*)(lds + n * DPAD) + e) =
        *((const h8*)(Wd + (size_t)(g * HD + j0 + u) * HD) + e);
  }
  float breg[4], wreg[4];
#pragma unroll
  for (int g = 0; g < 4; ++g) {
    breg[g] = biasD[g * HD + j0 + col];
    wreg[g] = wihD[g * HD + j0 + col];
  }
  const float fcw = fcW[j0 + col];
  const int arow = mb + wave * 16 + col;
  const int mrow = mb + wave * 16 + quad * 4;
  float cst[4];
#pragma unroll
  for (int r = 0; r < 4; ++r)
    cst[r] = aload_f32(&cD[(size_t)(mrow + r) * HD + j0 + col]);
  __syncthreads();

  for (int l = 0; l < L_; ++l) {
    const int par = l & 1;
    if (l > 0) wait_ge(decf + lane, (unsigned)l, true, 1 << 16);
    f4 A[32];
    ld32(hD + ((size_t)par * B_ + arow) * HD + quad * 8, A);
    f4 z = {0.f, 0.f, 0.f, 0.f};
    f4 acc[4] = {z, z, z, z};
#pragma unroll
    for (int kk = 0; kk < 32; ++kk) {
      h8 a = as_h8(A[kk]);
#pragma unroll
      for (int g = 0; g < 4; ++g) {
        h8 b = *((const h8*)(lds + (g * 16 + col) * DPAD) + kk * 4 + quad);
        acc[g] = __builtin_amdgcn_mfma_f32_16x16x32_f16(a, b, acc[g], 0, 0, 0);
      }
    }
    float pr[4];
#pragma unroll
    for (int r = 0; r < 4; ++r)
      pr[r] = (l > 0) ? aload_f32(&out[(size_t)(mrow + r) * L_ + (l - 1)]) : 0.f;

    float sum[4];
#pragma unroll
    for (int r = 0; r < 4; ++r) {
      float gi = acc[0][r] + breg[0] + pr[r] * wreg[0];
      float gf = acc[1][r] + breg[1] + pr[r] * wreg[1];
      float gg = acc[2][r] + breg[2] + pr[r] * wreg[2];
      float go = acc[3][r] + breg[3] + pr[r] * wreg[3];
      float c = sigm(gf) * cst[r] + sigm(gi) * tanh_(gg);
      cst[r] = c;
      float h = sigm(go) * tanh_(c);
      htile[wave * 16 + quad * 4 + r][col] = (_Float16)h;
      sum[r] = h * fcw;
    }
#pragma unroll
    for (int off = 1; off < 16; off <<= 1) {
#pragma unroll
      for (int r = 0; r < 4; ++r) sum[r] += __shfl_xor(sum[r], off, 16);
    }
    if (col == 0) {
#pragma unroll
      for (int r = 0; r < 4; ++r)
        atomicAdd(&out[(size_t)(mrow + r) * L_ + l], sum[r]);
    }
    __syncthreads();  // htile complete
    if (l < L_ - 1 && tid < 128) {
      int row = tid >> 1, half = tid & 1;
      const unsigned long long* src =
          (const unsigned long long*)&htile[row][half * 8];
      _Float16* dst = hD + ((size_t)(par ^ 1) * B_ + mb + row) * HD +
                      j0 + half * 8;
      astore_u64(dst, src[0]);
      astore_u64(dst + 4, src[1]);
    }
    vm_drain();       // every wave: drains its h stores AND out atomicAdds
    __syncthreads();
    if (tid == 0 && l < L_ - 1) astore_u32(decf + slice, (unsigned)(l + 1));
  }
}

// ---------------- persistent RNN kernel ----------------
__global__ __launch_bounds__(256, 1)
void rnn_kernel(const float* __restrict__ fcW, float* __restrict__ out,
                char* __restrict__ ws) {
  __shared__ __align__(16) _Float16 lds[64 * DPAD];   // 132096 B (weights)
  __shared__ __align__(16) _Float16 htile[64][16];    // 2 KB transpose tile
  __shared__ int sh[2];

  const int tid  = threadIdx.x;
  const int wave = tid >> 6;
  const int lane = tid & 63;
  const int quad = lane >> 4;
  const int col  = lane & 15;
  const int bi   = blockIdx.x;

  unsigned* sync = (unsigned*)(ws + OFF_SYNC);
  unsigned* gbar = sync + GBAR_IDX;
  unsigned* claim = sync + CLAIM_IDX;

  // ---- physical placement discovery ----
  if (tid == 0) {
    unsigned x;
    asm volatile("s_getreg_b32 %0, hwreg(HW_REG_XCC_ID)" : "=s"(x));
    int xcd = (int)(x & 7u);
    unsigned r = __hip_atomic_fetch_add(claim + xcd * 64, 1u, __ATOMIC_RELAXED,
                                        __HIP_MEMORY_SCOPE_AGENT);
    sh[0] = xcd;
    sh[1] = (int)r;
  }
  __syncthreads();
  const int xcd = sh[0], rank = sh[1];
  global_sync(gbar, 256u);  // all claims done
  if (tid == 0) {
    int d = 0;
    for (int k = 0; k < 8; ++k)
      if (aload_u32(claim + k * 64) != 32u) d = 1;
    sh[0] = d;
  }
  __syncthreads();
  const bool deg = (sh[0] != 0) || (rank >= 32);

  if (!deg)
    encoder_phase<true>(xcd >> 2, xcd & 3, rank, tid, wave, quad, col, lane,
                        ws, lds, htile);
  else
    encoder_phase<false>(bi >> 7, bi & 3, (bi & 127) >> 2, tid, wave, quad, col,
                         lane, ws, lds, htile);

  global_sync(gbar, 512u);  // encoder -> decoder handoff (hD/cD via L3)

  decoder_phase(bi >> 2, bi & 3, tid, wave, quad, col, lane, fcW, out, ws, lds,
                htile);
}

extern "C" void kernel_launch(void* const* d_in, const int* in_sizes, int n_in,
                              void* d_out, int out_size, void* d_ws, size_t ws_size,
                              hipStream_t stream) {
  const float* x     = (const float*)d_in[0];
  const float* eWihF = (const float*)d_in[1];
  const float* eWhhF = (const float*)d_in[2];
  const float* ebihF = (const float*)d_in[3];
  const float* ebhhF = (const float*)d_in[4];
  const float* eWihB = (const float*)d_in[5];
  const float* eWhhB = (const float*)d_in[6];
  const float* ebihB = (const float*)d_in[7];
  const float* ebhhB = (const float*)d_in[8];
  const float* dWih  = (const float*)d_in[9];
  const float* dWhh  = (const float*)d_in[10];
  const float* dbih  = (const float*)d_in[11];
  const float* dbhh  = (const float*)d_in[12];
  const float* fcW   = (const float*)d_in[13];
  const float* fcb   = (const float*)d_in[14];
  float* out = (float*)d_out;
  char*  ws  = (char*)d_ws;

  prep_misc<<<2048, 256, 0, stream>>>(ebihF, ebhhF, ebihB, ebhhB, dbih, dbhh,
                                      dWih, fcb, out, ws);
  conv_encw<<<(GE * KE) / 256, 256, 0, stream>>>(eWihF, eWhhF, eWihB, eWhhB, ws);
  conv_decw<<<(GD * HD) / 256, 256, 0, stream>>>(dWhh, ws);
  conv_x<<<(T_ * B_ * F_) / 256, 256, 0, stream>>>(x, ws);

  void* args[] = {(void*)&fcW, (void*)&out, (void*)&ws};
  hipError_t err = hipLaunchCooperativeKernel(rnn_kernel, dim3(256), dim3(256),
                                              args, 0, stream);
  if (err != hipSuccess) {
    // 256 blocks x 1 block/CU (LDS-forced) are co-resident under plain launch
    rnn_kernel<<<dim3(256), dim3(256), 0, stream>>>(fcW, out, ws);
  }
}

// Round 6
// 1477.921 us; speedup vs baseline: 4.4824x; 1.0167x over previous
//
#include <hip/hip_runtime.h>

// RNN_M2M: bidirectional LSTM encoder (T=168,B=256,F=128,H=512) + autoregressive
// LSTM decoder (hidden 1024, 48 steps) + scalar FC.
// R6 = R5 + (a) busy-spin polls (s_sleep removed -- suspected µs-scale wakeup
// quantization on the serial recurrence), (b) encoder h-part B-fragments held
// in 256 VGPRs per wave (zero LDS reads on the post-wait critical path).
// Encoder h-exchange XCD-local (physical XCC_ID claim, plain stores -> shared
// L2, sc0 loads, store-only flag lines). Decoder agent/L3 scope.

constexpr int B_ = 256, T_ = 168, F_ = 128, H_ = 512, L_ = 48;
constexpr int KE = F_ + H_;   // 640
constexpr int HD = 1024;
constexpr int GE = 4 * H_;    // 2048
constexpr int GD = 4 * HD;    // 4096
constexpr int EPAD = KE + 8;  // LDS stride (halves)
constexpr int DPAD = HD + 8;

// sync area (u32 indices into ws): 8 KB total
constexpr int GBAR_IDX = 0;     // global barrier counter (line 0)
constexpr int CLAIM_IDX = 64;   // claim[k] at CLAIM_IDX + k*64, k=0..7
constexpr int ENCF_IDX = 640;   // enc flags: + d*64 + s   (d=0..7, s=0..31)
constexpr int DECF_IDX = 1280;  // dec flags: + c*64 + s   (c=0..3, s=0..63)

// workspace layout (bytes)
constexpr size_t OFF_SYNC = 0;                                       // 8KB
constexpr size_t OFF_WCF = 8192;
constexpr size_t OFF_WCB = OFF_WCF + (size_t)GE * KE * 2;
constexpr size_t OFF_WD  = OFF_WCB + (size_t)GE * KE * 2;
constexpr size_t OFF_BF  = OFF_WD  + (size_t)GD * HD * 2;
constexpr size_t OFF_BB  = OFF_BF  + (size_t)GE * 4;
constexpr size_t OFF_BD  = OFF_BB  + (size_t)GE * 4;
constexpr size_t OFF_WIH = OFF_BD  + (size_t)GD * 4;
constexpr size_t OFF_XH  = OFF_WIH + (size_t)GD * 4;
constexpr size_t OFF_HE  = OFF_XH  + (size_t)T_ * B_ * F_ * 2;       // h enc fp16 [2 par][2 dir][B][H]
constexpr size_t OFF_HDD = OFF_HE  + (size_t)2 * 2 * B_ * H_ * 2;    // h dec fp16 [2 par][B][HD]
constexpr size_t OFF_CD  = OFF_HDD + (size_t)2 * B_ * HD * 2;        // c dec f32 [B][HD]

using h8 = __attribute__((ext_vector_type(8))) _Float16;
using f4 = __attribute__((ext_vector_type(4))) float;

#define DEV static __device__ __forceinline__

DEV float sigm(float x)  { return __fdividef(1.f, 1.f + __expf(-x)); }
DEV float tanh_(float x) { return 1.f - __fdividef(2.f, __expf(2.f * x) + 1.f); }

DEV h8 as_h8(f4 v) { union { f4 f; h8 h; } u; u.f = v; return u.h; }

// ---- agent-scope (L3-coherent) accessors ----
DEV void astore_u64(void* p, unsigned long long v) {
  __hip_atomic_store((unsigned long long*)p, v, __ATOMIC_RELAXED,
                     __HIP_MEMORY_SCOPE_AGENT);
}
DEV void astore_u32(void* p, unsigned v) {
  __hip_atomic_store((unsigned*)p, v, __ATOMIC_RELAXED, __HIP_MEMORY_SCOPE_AGENT);
}
DEV unsigned aload_u32(const void* p) {
  return __hip_atomic_load((const unsigned*)p, __ATOMIC_RELAXED,
                           __HIP_MEMORY_SCOPE_AGENT);
}
DEV float aload_f32(const void* p) {
  return __hip_atomic_load((const float*)p, __ATOMIC_RELAXED,
                           __HIP_MEMORY_SCOPE_AGENT);
}
DEV void astore_f32(void* p, float v) {
  __hip_atomic_store((float*)p, v, __ATOMIC_RELAXED, __HIP_MEMORY_SCOPE_AGENT);
}
DEV void vm_drain() { asm volatile("s_waitcnt vmcnt(0)" ::: "memory"); }

// ---- batched h loads: one asm block, single waitcnt ----
// "=&v" earlyclobber: outputs must NOT alias the address pair.
template<bool DEEP>
DEV void ld16(const _Float16* p, f4* A) {
#define L16(FL) asm volatile( \
    "global_load_dwordx4 %0,  %16, off" FL "\n\t" \
    "global_load_dwordx4 %1,  %16, off offset:64" FL "\n\t" \
    "global_load_dwordx4 %2,  %16, off offset:128" FL "\n\t" \
    "global_load_dwordx4 %3,  %16, off offset:192" FL "\n\t" \
    "global_load_dwordx4 %4,  %16, off offset:256" FL "\n\t" \
    "global_load_dwordx4 %5,  %16, off offset:320" FL "\n\t" \
    "global_load_dwordx4 %6,  %16, off offset:384" FL "\n\t" \
    "global_load_dwordx4 %7,  %16, off offset:448" FL "\n\t" \
    "global_load_dwordx4 %8,  %16, off offset:512" FL "\n\t" \
    "global_load_dwordx4 %9,  %16, off offset:576" FL "\n\t" \
    "global_load_dwordx4 %10, %16, off offset:640" FL "\n\t" \
    "global_load_dwordx4 %11, %16, off offset:704" FL "\n\t" \
    "global_load_dwordx4 %12, %16, off offset:768" FL "\n\t" \
    "global_load_dwordx4 %13, %16, off offset:832" FL "\n\t" \
    "global_load_dwordx4 %14, %16, off offset:896" FL "\n\t" \
    "global_load_dwordx4 %15, %16, off offset:960" FL "\n\t" \
    "s_waitcnt vmcnt(0)" \
    : "=&v"(A[0]),"=&v"(A[1]),"=&v"(A[2]),"=&v"(A[3]),"=&v"(A[4]),"=&v"(A[5]), \
      "=&v"(A[6]),"=&v"(A[7]),"=&v"(A[8]),"=&v"(A[9]),"=&v"(A[10]),"=&v"(A[11]), \
      "=&v"(A[12]),"=&v"(A[13]),"=&v"(A[14]),"=&v"(A[15]) \
    : "v"(p) : "memory")
  if constexpr (DEEP) { L16(" sc0 sc1"); } else { L16(" sc0"); }
#undef L16
}

DEV void ld32(const _Float16* p, f4* A) {
  asm volatile(
    "global_load_dwordx4 %0,  %32, off sc0 sc1\n\t"
    "global_load_dwordx4 %1,  %32, off offset:64 sc0 sc1\n\t"
    "global_load_dwordx4 %2,  %32, off offset:128 sc0 sc1\n\t"
    "global_load_dwordx4 %3,  %32, off offset:192 sc0 sc1\n\t"
    "global_load_dwordx4 %4,  %32, off offset:256 sc0 sc1\n\t"
    "global_load_dwordx4 %5,  %32, off offset:320 sc0 sc1\n\t"
    "global_load_dwordx4 %6,  %32, off offset:384 sc0 sc1\n\t"
    "global_load_dwordx4 %7,  %32, off offset:448 sc0 sc1\n\t"
    "global_load_dwordx4 %8,  %32, off offset:512 sc0 sc1\n\t"
    "global_load_dwordx4 %9,  %32, off offset:576 sc0 sc1\n\t"
    "global_load_dwordx4 %10, %32, off offset:640 sc0 sc1\n\t"
    "global_load_dwordx4 %11, %32, off offset:704 sc0 sc1\n\t"
    "global_load_dwordx4 %12, %32, off offset:768 sc0 sc1\n\t"
    "global_load_dwordx4 %13, %32, off offset:832 sc0 sc1\n\t"
    "global_load_dwordx4 %14, %32, off offset:896 sc0 sc1\n\t"
    "global_load_dwordx4 %15, %32, off offset:960 sc0 sc1\n\t"
    "global_load_dwordx4 %16, %32, off offset:1024 sc0 sc1\n\t"
    "global_load_dwordx4 %17, %32, off offset:1088 sc0 sc1\n\t"
    "global_load_dwordx4 %18, %32, off offset:1152 sc0 sc1\n\t"
    "global_load_dwordx4 %19, %32, off offset:1216 sc0 sc1\n\t"
    "global_load_dwordx4 %20, %32, off offset:1280 sc0 sc1\n\t"
    "global_load_dwordx4 %21, %32, off offset:1344 sc0 sc1\n\t"
    "global_load_dwordx4 %22, %32, off offset:1408 sc0 sc1\n\t"
    "global_load_dwordx4 %23, %32, off offset:1472 sc0 sc1\n\t"
    "global_load_dwordx4 %24, %32, off offset:1536 sc0 sc1\n\t"
    "global_load_dwordx4 %25, %32, off offset:1600 sc0 sc1\n\t"
    "global_load_dwordx4 %26, %32, off offset:1664 sc0 sc1\n\t"
    "global_load_dwordx4 %27, %32, off offset:1728 sc0 sc1\n\t"
    "global_load_dwordx4 %28, %32, off offset:1792 sc0 sc1\n\t"
    "global_load_dwordx4 %29, %32, off offset:1856 sc0 sc1\n\t"
    "global_load_dwordx4 %30, %32, off offset:1920 sc0 sc1\n\t"
    "global_load_dwordx4 %31, %32, off offset:1984 sc0 sc1\n\t"
    "s_waitcnt vmcnt(0)"
    : "=&v"(A[0]),"=&v"(A[1]),"=&v"(A[2]),"=&v"(A[3]),"=&v"(A[4]),"=&v"(A[5]),
      "=&v"(A[6]),"=&v"(A[7]),"=&v"(A[8]),"=&v"(A[9]),"=&v"(A[10]),"=&v"(A[11]),
      "=&v"(A[12]),"=&v"(A[13]),"=&v"(A[14]),"=&v"(A[15]),"=&v"(A[16]),"=&v"(A[17]),
      "=&v"(A[18]),"=&v"(A[19]),"=&v"(A[20]),"=&v"(A[21]),"=&v"(A[22]),"=&v"(A[23]),
      "=&v"(A[24]),"=&v"(A[25]),"=&v"(A[26]),"=&v"(A[27]),"=&v"(A[28]),"=&v"(A[29]),
      "=&v"(A[30]),"=&v"(A[31])
    : "v"(p) : "memory");
}

// flag poll: bounded, lane-parallel, ballot-complete. BUSY SPIN (no s_sleep).
DEV unsigned pollflag(const unsigned* p, bool deep) {
  unsigned v;
  if (deep)
    asm volatile("global_load_dword %0, %1, off sc0 sc1\n\t"
                 "s_waitcnt vmcnt(0)" : "=&v"(v) : "v"(p) : "memory");
  else
    asm volatile("global_load_dword %0, %1, off sc0\n\t"
                 "s_waitcnt vmcnt(0)" : "=&v"(v) : "v"(p) : "memory");
  return v;
}
DEV void wait_ge(const unsigned* p, unsigned target, bool deep, int cap) {
  for (int it = 0; it < cap; ++it) {
    unsigned v = pollflag(p, deep);
    if (__ballot(v >= target) == ~0ull) return;
  }
}

// global barrier (agent scope, monotone target); bounded busy spin
DEV void global_sync(unsigned* cnt, unsigned target) {
  vm_drain();
  __syncthreads();
  if (threadIdx.x == 0) {
    __hip_atomic_fetch_add(cnt, 1u, __ATOMIC_RELAXED, __HIP_MEMORY_SCOPE_AGENT);
    for (int it = 0; it < (1 << 20); ++it) {
      if (aload_u32(cnt) >= target) break;
    }
  }
  __syncthreads();
  asm volatile("" ::: "memory");
}

// ---------------- prep kernels ----------------
__global__ void prep_misc(const float* bihF, const float* bhhF,
                          const float* bihB, const float* bhhB,
                          const float* dbih, const float* dbhh,
                          const float* dwih, const float* fcb,
                          float* out, char* ws) {
  int i = blockIdx.x * blockDim.x + threadIdx.x;
  if (i < 1024) astore_u64(ws + (size_t)i * 8, 0ull);  // 8KB sync area
  if (i < GE) {
    ((float*)(ws + OFF_BF))[i] = bihF[i] + bhhF[i];
    ((float*)(ws + OFF_BB))[i] = bihB[i] + bhhB[i];
  }
  if (i < GD) {
    ((float*)(ws + OFF_BD))[i]  = dbih[i] + dbhh[i];
    ((float*)(ws + OFF_WIH))[i] = dwih[i];
  }
  if (i < B_ * L_) out[i] = fcb[0];
  // zero h buffers through L3 so cold L2/L3 reads see them
  if (i < 2 * 2 * B_ * H_ / 4) astore_u64((char*)ws + OFF_HE + (size_t)i * 8, 0ull);
}

__global__ void conv_encw(const float* WihF, const float* WhhF,
                          const float* WihB, const float* WhhB, char* ws) {
  int i = blockIdx.x * blockDim.x + threadIdx.x;
  if (i >= GE * KE) return;
  int r = i / KE, k = i - r * KE;
  float vF = (k < F_) ? WihF[r * F_ + k] : WhhF[r * H_ + (k - F_)];
  float vB = (k < F_) ? WihB[r * F_ + k] : WhhB[r * H_ + (k - F_)];
  ((_Float16*)(ws + OFF_WCF))[i] = (_Float16)vF;
  ((_Float16*)(ws + OFF_WCB))[i] = (_Float16)vB;
}

__global__ void conv_decw(const float* W, char* ws) {
  int i = blockIdx.x * blockDim.x + threadIdx.x;
  if (i < GD * HD) ((_Float16*)(ws + OFF_WD))[i] = (_Float16)W[i];
}

__global__ void conv_x(const float* x, char* ws) {
  int i = blockIdx.x * blockDim.x + threadIdx.x;
  if (i >= T_ * B_ * F_) return;
  int f = i & 127, b = (i >> 7) & 255, t = i >> 15;
  ((_Float16*)(ws + OFF_XH))[i] = (_Float16)x[((size_t)b * T_ + t) * F_ + f];
}

// ---------------- encoder phase ----------------
template<bool LOCAL>
DEV void encoder_phase(int dir, int chunk, int slice,
                       int tid, int wave, int quad, int col, int lane,
                       char* ws, _Float16* lds, _Float16 (*htile)[16]) {
  const _Float16* Wenc  = (const _Float16*)(ws + (dir ? OFF_WCB : OFF_WCF));
  const float*    biasE = (const float*)(ws + (dir ? OFF_BB : OFF_BF));
  const _Float16* Xh    = (const _Float16*)(ws + OFF_XH);
  _Float16* hE = (_Float16*)(ws + OFF_HE);
  _Float16* hD = (_Float16*)(ws + OFF_HDD);
  float*    cD = (float*)(ws + OFF_CD);
  unsigned* encf = (unsigned*)ws + ENCF_IDX + (dir * 4 + chunk) * 64;

  const int j0 = slice * 16;
  const int mb = chunk * 64;

  for (int it = 0; it < 20; ++it) {   // stage 64 gate rows x 640 K into LDS
    int idx = it * 256 + tid;
    int n = idx / 80, e = idx - n * 80;
    int g = n >> 4, u = n & 15;
    *((h8*)(lds + n * EPAD) + e) =
        *((const h8*)(Wenc + (size_t)(g * H_ + j0 + u) * KE) + e);
  }
  float breg[4];
#pragma unroll
  for (int g = 0; g < 4; ++g) breg[g] = biasE[g * H_ + j0 + col];
  float cst[4] = {0.f, 0.f, 0.f, 0.f};
  __syncthreads();

  // h-part B-fragments -> registers (256 VGPR): zero LDS on the critical path
  h8 Bf[4][16];
#pragma unroll
  for (int g = 0; g < 4; ++g)
#pragma unroll
    for (int kk = 0; kk < 16; ++kk)
      Bf[g][kk] = *((const h8*)(lds + (g * 16 + col) * EPAD + F_) + kk * 4 + quad);

  const int arow = mb + wave * 16 + col;
  const int mrow = mb + wave * 16 + quad * 4;

  for (int t = 0; t < T_; ++t) {
    const int par = t & 1;
    const int tx  = dir ? (T_ - 1 - t) : t;
    f4 z = {0.f, 0.f, 0.f, 0.f};
    f4 acc[4] = {z, z, z, z};

    // x part (K=128, LDS B, cached x reads) — latency filler before the wait
    const h8* xr = (const h8*)(Xh + ((size_t)tx * B_ + arow) * F_);
#pragma unroll
    for (int kk = 0; kk < 4; ++kk) {
      h8 a = xr[kk * 4 + quad];
#pragma unroll
      for (int g = 0; g < 4; ++g) {
        h8 b = *((const h8*)(lds + (g * 16 + col) * EPAD) + kk * 4 + quad);
        acc[g] = __builtin_amdgcn_mfma_f32_16x16x32_f16(a, b, acc[g], 0, 0, 0);
      }
    }
    // wait for peers' h of this step
    if (t > 0)
      wait_ge(encf + (lane & 31), (unsigned)t, !LOCAL, 1 << 16);
    // h part (K=512): batched global loads + register B -> pure MFMA
    f4 A[16];
    ld16<!LOCAL>(hE + ((size_t)(par * 2 + dir) * B_ + arow) * H_ + quad * 8, A);
#pragma unroll
    for (int kk = 0; kk < 16; ++kk) {
      h8 a = as_h8(A[kk]);
#pragma unroll
      for (int g = 0; g < 4; ++g)
        acc[g] = __builtin_amdgcn_mfma_f32_16x16x32_f16(a, Bf[g][kk], acc[g], 0, 0, 0);
    }

#pragma unroll
    for (int r = 0; r < 4; ++r) {
      float gi = acc[0][r] + breg[0];
      float gf = acc[1][r] + breg[1];
      float gg = acc[2][r] + breg[2];
      float go = acc[3][r] + breg[3];
      float c = sigm(gf) * cst[r] + sigm(gi) * tanh_(gg);
      cst[r] = c;
      float h = sigm(go) * tanh_(c);
      htile[wave * 16 + quad * 4 + r][col] = (_Float16)h;
      if (t == T_ - 1)
        astore_f32(&cD[(size_t)(mrow + r) * HD + dir * H_ + j0 + col], c);
    }
    __syncthreads();  // htile complete
    if (tid < 128) {  // 64 rows x 32B/row; 2 threads/row x 16B
      int row = tid >> 1, half = tid & 1;
      const unsigned long long* src =
          (const unsigned long long*)&htile[row][half * 8];
      if (t < T_ - 1) {
        _Float16* dst = hE + ((size_t)((par ^ 1) * 2 + dir) * B_ + mb + row) * H_ +
                        j0 + half * 8;
        if (LOCAL) {  // plain stores -> shared XCD L2 (L1 is write-through)
          ((unsigned long long*)dst)[0] = src[0];
          ((unsigned long long*)(dst + 4))[0] = src[1];
        } else {
          astore_u64(dst, src[0]);
          astore_u64(dst + 4, src[1]);
        }
      } else {        // final h -> decoder buffer, must cross XCDs
        _Float16* dst = hD + (size_t)(mb + row) * HD + dir * H_ + j0 + half * 8;
        astore_u64(dst, src[0]);
        astore_u64(dst + 4, src[1]);
      }
    }
    vm_drain();       // all waves: h (and cD) stores complete
    __syncthreads();  // htile consumed + all drains done
    if (tid == 0 && t < T_ - 1) {
      if (LOCAL) *(volatile unsigned*)(encf + slice) = (unsigned)(t + 1);
      else       astore_u32(encf + slice, (unsigned)(t + 1));
    }
  }
}

// ---------------- decoder phase (agent/L3 scope) ----------------
DEV void decoder_phase(int slice, int chunk,
                       int tid, int wave, int quad, int col, int lane,
                       const float* fcW, float* out, char* ws,
                       _Float16* lds, _Float16 (*htile)[16]) {
  const _Float16* Wd    = (const _Float16*)(ws + OFF_WD);
  const float*    biasD = (const float*)(ws + OFF_BD);
  const float*    wihD  = (const float*)(ws + OFF_WIH);
  _Float16* hD = (_Float16*)(ws + OFF_HDD);
  float*    cD = (float*)(ws + OFF_CD);
  unsigned* decf = (unsigned*)ws + DECF_IDX + chunk * 64;

  const int j0 = slice * 16;
  const int mb = chunk * 64;

  for (int it = 0; it < 32; ++it) {  // stage 64 x 1024 dec weight rows
    int idx = it * 256 + tid;
    int n = idx >> 7, e = idx & 127;
    int g = n >> 4, u = n & 15;
    *((h8*)(lds + n * DPAD) + e) =
        *((const h8*)(Wd + (size_t)(g * HD + j0 + u) * HD) + e);
  }
  float breg[4], wreg[4];
#pragma unroll
  for (int g = 0; g < 4; ++g) {
    breg[g] = biasD[g * HD + j0 + col];
    wreg[g] = wihD[g * HD + j0 + col];
  }
  const float fcw = fcW[j0 + col];
  const int arow = mb + wave * 16 + col;
  const int mrow = mb + wave * 16 + quad * 4;
  float cst[4];
#pragma unroll
  for (int r = 0; r < 4; ++r)
    cst[r] = aload_f32(&cD[(size_t)(mrow + r) * HD + j0 + col]);
  __syncthreads();

  for (int l = 0; l < L_; ++l) {
    const int par = l & 1;
    if (l > 0) wait_ge(decf + lane, (unsigned)l, true, 1 << 16);
    f4 A[32];
    ld32(hD + ((size_t)par * B_ + arow) * HD + quad * 8, A);
    f4 z = {0.f, 0.f, 0.f, 0.f};
    f4 acc[4] = {z, z, z, z};
#pragma unroll
    for (int kk = 0; kk < 32; ++kk) {
      h8 a = as_h8(A[kk]);
#pragma unroll
      for (int g = 0; g < 4; ++g) {
        h8 b = *((const h8*)(lds + (g * 16 + col) * DPAD) + kk * 4 + quad);
        acc[g] = __builtin_amdgcn_mfma_f32_16x16x32_f16(a, b, acc[g], 0, 0, 0);
      }
    }
    float pr[4];
#pragma unroll
    for (int r = 0; r < 4; ++r)
      pr[r] = (l > 0) ? aload_f32(&out[(size_t)(mrow + r) * L_ + (l - 1)]) : 0.f;

    float sum[4];
#pragma unroll
    for (int r = 0; r < 4; ++r) {
      float gi = acc[0][r] + breg[0] + pr[r] * wreg[0];
      float gf = acc[1][r] + breg[1] + pr[r] * wreg[1];
      float gg = acc[2][r] + breg[2] + pr[r] * wreg[2];
      float go = acc[3][r] + breg[3] + pr[r] * wreg[3];
      float c = sigm(gf) * cst[r] + sigm(gi) * tanh_(gg);
      cst[r] = c;
      float h = sigm(go) * tanh_(c);
      htile[wave * 16 + quad * 4 + r][col] = (_Float16)h;
      sum[r] = h * fcw;
    }
#pragma unroll
    for (int off = 1; off < 16; off <<= 1) {
#pragma unroll
      for (int r = 0; r < 4; ++r) sum[r] += __shfl_xor(sum[r], off, 16);
    }
    if (col == 0) {
#pragma unroll
      for (int r = 0; r < 4; ++r)
        atomicAdd(&out[(size_t)(mrow + r) * L_ + l], sum[r]);
    }
    __syncthreads();  // htile complete
    if (l < L_ - 1 && tid < 128) {
      int row = tid >> 1, half = tid & 1;
      const unsigned long long* src =
          (const unsigned long long*)&htile[row][half * 8];
      _Float16* dst = hD + ((size_t)(par ^ 1) * B_ + mb + row) * HD +
                      j0 + half * 8;
      astore_u64(dst, src[0]);
      astore_u64(dst + 4, src[1]);
    }
    vm_drain();       // every wave: drains its h stores AND out atomicAdds
    __syncthreads();
    if (tid == 0 && l < L_ - 1) astore_u32(decf + slice, (unsigned)(l + 1));
  }
}

// ---------------- persistent RNN kernel ----------------
__global__ __launch_bounds__(256, 1)
void rnn_kernel(const float* __restrict__ fcW, float* __restrict__ out,
                char* __restrict__ ws) {
  __shared__ __align__(16) _Float16 lds[64 * DPAD];   // 132096 B (weights)
  __shared__ __align__(16) _Float16 htile[64][16];    // 2 KB transpose tile
  __shared__ int sh[2];

  const int tid  = threadIdx.x;
  const int wave = tid >> 6;
  const int lane = tid & 63;
  const int quad = lane >> 4;
  const int col  = lane & 15;
  const int bi   = blockIdx.x;

  unsigned* sync = (unsigned*)(ws + OFF_SYNC);
  unsigned* gbar = sync + GBAR_IDX;
  unsigned* claim = sync + CLAIM_IDX;

  // ---- physical placement discovery ----
  if (tid == 0) {
    unsigned x;
    asm volatile("s_getreg_b32 %0, hwreg(HW_REG_XCC_ID)" : "=s"(x));
    int xcd = (int)(x & 7u);
    unsigned r = __hip_atomic_fetch_add(claim + xcd * 64, 1u, __ATOMIC_RELAXED,
                                        __HIP_MEMORY_SCOPE_AGENT);
    sh[0] = xcd;
    sh[1] = (int)r;
  }
  __syncthreads();
  const int xcd = sh[0], rank = sh[1];
  global_sync(gbar, 256u);  // all claims done
  if (tid == 0) {
    int d = 0;
    for (int k = 0; k < 8; ++k)
      if (aload_u32(claim + k * 64) != 32u) d = 1;
    sh[0] = d;
  }
  __syncthreads();
  const bool deg = (sh[0] != 0) || (rank >= 32);

  if (!deg)
    encoder_phase<true>(xcd >> 2, xcd & 3, rank, tid, wave, quad, col, lane,
                        ws, lds, htile);
  else
    encoder_phase<false>(bi >> 7, bi & 3, (bi & 127) >> 2, tid, wave, quad, col,
                         lane, ws, lds, htile);

  global_sync(gbar, 512u);  // encoder -> decoder handoff (hD/cD via L3)

  decoder_phase(bi >> 2, bi & 3, tid, wave, quad, col, lane, fcW, out, ws, lds,
                htile);
}

extern "C" void kernel_launch(void* const* d_in, const int* in_sizes, int n_in,
                              void* d_out, int out_size, void* d_ws, size_t ws_size,
                              hipStream_t stream) {
  const float* x     = (const float*)d_in[0];
  const float* eWihF = (const float*)d_in[1];
  const float* eWhhF = (const float*)d_in[2];
  const float* ebihF = (const float*)d_in[3];
  const float* ebhhF = (const float*)d_in[4];
  const float* eWihB = (const float*)d_in[5];
  const float* eWhhB = (const float*)d_in[6];
  const float* ebihB = (const float*)d_in[7];
  const float* ebhhB = (const float*)d_in[8];
  const float* dWih  = (const float*)d_in[9];
  const float* dWhh  = (const float*)d_in[10];
  const float* dbih  = (const float*)d_in[11];
  const float* dbhh  = (const float*)d_in[12];
  const float* fcW   = (const float*)d_in[13];
  const float* fcb   = (const float*)d_in[14];
  float* out = (float*)d_out;
  char*  ws  = (char*)d_ws;

  prep_misc<<<2048, 256, 0, stream>>>(ebihF, ebhhF, ebihB, ebhhB, dbih, dbhh,
                                      dWih, fcb, out, ws);
  conv_encw<<<(GE * KE) / 256, 256, 0, stream>>>(eWihF, eWhhF, eWihB, eWhhB, ws);
  conv_decw<<<(GD * HD) / 256, 256, 0, stream>>>(dWhh, ws);
  conv_x<<<(T_ * B_ * F_) / 256, 256, 0, stream>>>(x, ws);

  void* args[] = {(void*)&fcW, (void*)&out, (void*)&ws};
  hipError_t err = hipLaunchCooperativeKernel(rnn_kernel, dim3(256), dim3(256),
                                              args, 0, stream);
  if (err != hipSuccess) {
    // 256 blocks x 1 block/CU (LDS-forced) are co-resident under plain launch
    rnn_kernel<<<dim3(256), dim3(256), 0, stream>>>(fcW, out, ws);
  }
}

// Round 9
// 1475.672 us; speedup vs baseline: 4.4893x; 1.0015x over previous
//
#include <hip/hip_runtime.h>

// RNN_M2M: bidirectional LSTM encoder (T=168,B=256,F=128,H=512) + autoregressive
// LSTM decoder (hidden 1024, 48 steps) + scalar FC.
// R9 = R8 with the decoder FORCED to DEEP (agent/L3) exchange -- controlled
// bisection: R8's 0.096 absmax is either (a) the LOCAL plain-store/sc0
// protocol in the decoder, or (b) a structural bug in the new decoder
// (split LDS/VGPR weights, PP partial-sum feedback). DEEP is the accessor
// class R5 passed with (9.8e-4), so PASS here => (a), FAIL => (b).
// Decoder structure unchanged from R8: XCD-owned 32 batch rows, 32 blocks x
// 32 hidden units, gates i,f in LDS / g,o staged per-wave, PP double-buffered
// pred partials, store-only flag sync, direct out[] writes.
// Encoder unchanged (XCD-local, R5/R6-proven).

constexpr int B_ = 256, T_ = 168, F_ = 128, H_ = 512, L_ = 48;
constexpr int KE = F_ + H_;   // 640
constexpr int HD = 1024;
constexpr int GE = 4 * H_;    // 2048
constexpr int EPAD = KE + 8;  // LDS stride (halves)
constexpr int DPAD = HD + 8;

// sync area (u32 indices into ws): 8 KB
constexpr int FL256_IDX = 0;    // 256 per-block barrier flags
constexpr int CLAIM_IDX = 256;  // claim[k] at + k*64, k=0..7
constexpr int ENCF_IDX  = 768;  // enc flags: + d*64 + s (d=0..7, s=0..31)
constexpr int DECF_IDX  = 1280; // dec flags: + x*64 + r (x=0..7, r=0..31)

// workspace layout (bytes)
constexpr size_t OFF_SYNC = 0;                                       // 8KB
constexpr size_t OFF_WCF = 8192;                                     // enc fwd [Wih|Whh] fp16
constexpr size_t OFF_WCB = OFF_WCF + (size_t)GE * KE * 2;            // enc bwd
constexpr size_t OFF_PP  = OFF_WCB + (size_t)GE * KE * 2;            // pred partials [8 xcd][2 buf][64 part][32 row] f32
constexpr size_t OFF_BF  = OFF_PP  + (size_t)8 * 2 * 64 * 32 * 4;    // enc fwd bias f32
constexpr size_t OFF_BB  = OFF_BF  + (size_t)GE * 4;
constexpr size_t OFF_XH  = OFF_BB  + (size_t)GE * 4;                 // x fp16 [T][B][F]
constexpr size_t OFF_HE  = OFF_XH  + (size_t)T_ * B_ * F_ * 2;       // h enc fp16 [2 par][2 dir][B][H]
constexpr size_t OFF_HDD = OFF_HE  + (size_t)2 * 2 * B_ * H_ * 2;    // h dec fp16 [2 par][B][HD]
constexpr size_t OFF_CD  = OFF_HDD + (size_t)2 * B_ * HD * 2;        // c dec f32 [B][HD]

using h8 = __attribute__((ext_vector_type(8))) _Float16;
using f4 = __attribute__((ext_vector_type(4))) float;
using u4 = __attribute__((ext_vector_type(4))) unsigned;

#define DEV static __device__ __forceinline__

DEV float sigm(float x)  { return __fdividef(1.f, 1.f + __expf(-x)); }
DEV float tanh_(float x) { return 1.f - __fdividef(2.f, __expf(2.f * x) + 1.f); }

DEV h8 as_h8(f4 v) { union { f4 f; h8 h; } u; u.f = v; return u.h; }

// ---- agent-scope (L3-coherent) accessors ----
DEV void astore_u64(void* p, unsigned long long v) {
  __hip_atomic_store((unsigned long long*)p, v, __ATOMIC_RELAXED,
                     __HIP_MEMORY_SCOPE_AGENT);
}
DEV void astore_u32(void* p, unsigned v) {
  __hip_atomic_store((unsigned*)p, v, __ATOMIC_RELAXED, __HIP_MEMORY_SCOPE_AGENT);
}
DEV unsigned aload_u32(const void* p) {
  return __hip_atomic_load((const unsigned*)p, __ATOMIC_RELAXED,
                           __HIP_MEMORY_SCOPE_AGENT);
}
DEV float aload_f32(const void* p) {
  return __hip_atomic_load((const float*)p, __ATOMIC_RELAXED,
                           __HIP_MEMORY_SCOPE_AGENT);
}
DEV void astore_f32(void* p, float v) {
  __hip_atomic_store((float*)p, v, __ATOMIC_RELAXED, __HIP_MEMORY_SCOPE_AGENT);
}
DEV void astore_u16(void* p, _Float16 v) {
  union { _Float16 h; unsigned short s; } u; u.h = v;
  __hip_atomic_store((unsigned short*)p, u.s, __ATOMIC_RELAXED,
                     __HIP_MEMORY_SCOPE_AGENT);
}
DEV void vm_drain() { asm volatile("s_waitcnt vmcnt(0)" ::: "memory"); }

// ---- batched loads, one waitcnt; "=&v" earlyclobber mandatory ----
template<bool DEEP>
DEV void ld16(const _Float16* p, f4* A) {
#define L16(FL) asm volatile( \
    "global_load_dwordx4 %0,  %16, off" FL "\n\t" \
    "global_load_dwordx4 %1,  %16, off offset:64" FL "\n\t" \
    "global_load_dwordx4 %2,  %16, off offset:128" FL "\n\t" \
    "global_load_dwordx4 %3,  %16, off offset:192" FL "\n\t" \
    "global_load_dwordx4 %4,  %16, off offset:256" FL "\n\t" \
    "global_load_dwordx4 %5,  %16, off offset:320" FL "\n\t" \
    "global_load_dwordx4 %6,  %16, off offset:384" FL "\n\t" \
    "global_load_dwordx4 %7,  %16, off offset:448" FL "\n\t" \
    "global_load_dwordx4 %8,  %16, off offset:512" FL "\n\t" \
    "global_load_dwordx4 %9,  %16, off offset:576" FL "\n\t" \
    "global_load_dwordx4 %10, %16, off offset:640" FL "\n\t" \
    "global_load_dwordx4 %11, %16, off offset:704" FL "\n\t" \
    "global_load_dwordx4 %12, %16, off offset:768" FL "\n\t" \
    "global_load_dwordx4 %13, %16, off offset:832" FL "\n\t" \
    "global_load_dwordx4 %14, %16, off offset:896" FL "\n\t" \
    "global_load_dwordx4 %15, %16, off offset:960" FL "\n\t" \
    "s_waitcnt vmcnt(0)" \
    : "=&v"(A[0]),"=&v"(A[1]),"=&v"(A[2]),"=&v"(A[3]),"=&v"(A[4]),"=&v"(A[5]), \
      "=&v"(A[6]),"=&v"(A[7]),"=&v"(A[8]),"=&v"(A[9]),"=&v"(A[10]),"=&v"(A[11]), \
      "=&v"(A[12]),"=&v"(A[13]),"=&v"(A[14]),"=&v"(A[15]) \
    : "v"(p) : "memory")
  if constexpr (DEEP) { L16(" sc0 sc1"); } else { L16(" sc0"); }
#undef L16
}

template<bool DEEP>
DEV void ld32(const _Float16* p, f4* A) {
#define L32(FL) asm volatile( \
    "global_load_dwordx4 %0,  %32, off" FL "\n\t" \
    "global_load_dwordx4 %1,  %32, off offset:64" FL "\n\t" \
    "global_load_dwordx4 %2,  %32, off offset:128" FL "\n\t" \
    "global_load_dwordx4 %3,  %32, off offset:192" FL "\n\t" \
    "global_load_dwordx4 %4,  %32, off offset:256" FL "\n\t" \
    "global_load_dwordx4 %5,  %32, off offset:320" FL "\n\t" \
    "global_load_dwordx4 %6,  %32, off offset:384" FL "\n\t" \
    "global_load_dwordx4 %7,  %32, off offset:448" FL "\n\t" \
    "global_load_dwordx4 %8,  %32, off offset:512" FL "\n\t" \
    "global_load_dwordx4 %9,  %32, off offset:576" FL "\n\t" \
    "global_load_dwordx4 %10, %32, off offset:640" FL "\n\t" \
    "global_load_dwordx4 %11, %32, off offset:704" FL "\n\t" \
    "global_load_dwordx4 %12, %32, off offset:768" FL "\n\t" \
    "global_load_dwordx4 %13, %32, off offset:832" FL "\n\t" \
    "global_load_dwordx4 %14, %32, off offset:896" FL "\n\t" \
    "global_load_dwordx4 %15, %32, off offset:960" FL "\n\t" \
    "global_load_dwordx4 %16, %32, off offset:1024" FL "\n\t" \
    "global_load_dwordx4 %17, %32, off offset:1088" FL "\n\t" \
    "global_load_dwordx4 %18, %32, off offset:1152" FL "\n\t" \
    "global_load_dwordx4 %19, %32, off offset:1216" FL "\n\t" \
    "global_load_dwordx4 %20, %32, off offset:1280" FL "\n\t" \
    "global_load_dwordx4 %21, %32, off offset:1344" FL "\n\t" \
    "global_load_dwordx4 %22, %32, off offset:1408" FL "\n\t" \
    "global_load_dwordx4 %23, %32, off offset:1472" FL "\n\t" \
    "global_load_dwordx4 %24, %32, off offset:1536" FL "\n\t" \
    "global_load_dwordx4 %25, %32, off offset:1600" FL "\n\t" \
    "global_load_dwordx4 %26, %32, off offset:1664" FL "\n\t" \
    "global_load_dwordx4 %27, %32, off offset:1728" FL "\n\t" \
    "global_load_dwordx4 %28, %32, off offset:1792" FL "\n\t" \
    "global_load_dwordx4 %29, %32, off offset:1856" FL "\n\t" \
    "global_load_dwordx4 %30, %32, off offset:1920" FL "\n\t" \
    "global_load_dwordx4 %31, %32, off offset:1984" FL "\n\t" \
    "s_waitcnt vmcnt(0)" \
    : "=&v"(A[0]),"=&v"(A[1]),"=&v"(A[2]),"=&v"(A[3]),"=&v"(A[4]),"=&v"(A[5]), \
      "=&v"(A[6]),"=&v"(A[7]),"=&v"(A[8]),"=&v"(A[9]),"=&v"(A[10]),"=&v"(A[11]), \
      "=&v"(A[12]),"=&v"(A[13]),"=&v"(A[14]),"=&v"(A[15]),"=&v"(A[16]),"=&v"(A[17]), \
      "=&v"(A[18]),"=&v"(A[19]),"=&v"(A[20]),"=&v"(A[21]),"=&v"(A[22]),"=&v"(A[23]), \
      "=&v"(A[24]),"=&v"(A[25]),"=&v"(A[26]),"=&v"(A[27]),"=&v"(A[28]),"=&v"(A[29]), \
      "=&v"(A[30]),"=&v"(A[31]) \
    : "v"(p) : "memory")
  if constexpr (DEEP) { L32(" sc0 sc1"); } else { L32(" sc0"); }
#undef L32
}

// 16 scalar f32 loads at 128B stride, single waitcnt (pred-partial recon)
template<bool DEEP>
DEV void ld16s(const float* p, float* v) {
#define L16S(FL) asm volatile( \
    "global_load_dword %0,  %16, off" FL "\n\t" \
    "global_load_dword %1,  %16, off offset:128" FL "\n\t" \
    "global_load_dword %2,  %16, off offset:256" FL "\n\t" \
    "global_load_dword %3,  %16, off offset:384" FL "\n\t" \
    "global_load_dword %4,  %16, off offset:512" FL "\n\t" \
    "global_load_dword %5,  %16, off offset:640" FL "\n\t" \
    "global_load_dword %6,  %16, off offset:768" FL "\n\t" \
    "global_load_dword %7,  %16, off offset:896" FL "\n\t" \
    "global_load_dword %8,  %16, off offset:1024" FL "\n\t" \
    "global_load_dword %9,  %16, off offset:1152" FL "\n\t" \
    "global_load_dword %10, %16, off offset:1280" FL "\n\t" \
    "global_load_dword %11, %16, off offset:1408" FL "\n\t" \
    "global_load_dword %12, %16, off offset:1536" FL "\n\t" \
    "global_load_dword %13, %16, off offset:1664" FL "\n\t" \
    "global_load_dword %14, %16, off offset:1792" FL "\n\t" \
    "global_load_dword %15, %16, off offset:1920" FL "\n\t" \
    "s_waitcnt vmcnt(0)" \
    : "=&v"(v[0]),"=&v"(v[1]),"=&v"(v[2]),"=&v"(v[3]),"=&v"(v[4]),"=&v"(v[5]), \
      "=&v"(v[6]),"=&v"(v[7]),"=&v"(v[8]),"=&v"(v[9]),"=&v"(v[10]),"=&v"(v[11]), \
      "=&v"(v[12]),"=&v"(v[13]),"=&v"(v[14]),"=&v"(v[15]) \
    : "v"(p) : "memory")
  if constexpr (DEEP) { L16S(" sc0 sc1"); } else { L16S(" sc0"); }
#undef L16S
}

// flag poll: bounded, lane-parallel, ballot-complete (busy spin)
DEV unsigned pollflag(const unsigned* p, bool deep) {
  unsigned v;
  if (deep)
    asm volatile("global_load_dword %0, %1, off sc0 sc1\n\t"
                 "s_waitcnt vmcnt(0)" : "=&v"(v) : "v"(p) : "memory");
  else
    asm volatile("global_load_dword %0, %1, off sc0\n\t"
                 "s_waitcnt vmcnt(0)" : "=&v"(v) : "v"(p) : "memory");
  return v;
}
DEV void wait_ge(const unsigned* p, unsigned target, bool deep, int cap) {
  for (int it = 0; it < cap; ++it) {
    unsigned v = pollflag(p, deep);
    if (__ballot(v >= target) == ~0ull) return;
  }
}

// store/poll global barrier (no RMW serialization): 256 flags, 4/lane dwordx4
DEV void gsync(unsigned* fl, int bi, unsigned phase, int tid) {
  vm_drain();
  __syncthreads();
  if (tid == 0) astore_u32(fl + bi, phase);
  if (tid < 64) {
    const unsigned* p = fl + tid * 4;
    for (int it = 0; it < (1 << 20); ++it) {
      u4 v;
      asm volatile("global_load_dwordx4 %0, %1, off sc0 sc1\n\t"
                   "s_waitcnt vmcnt(0)" : "=&v"(v) : "v"(p) : "memory");
      unsigned a = v[0] < v[1] ? v[0] : v[1];
      unsigned b = v[2] < v[3] ? v[2] : v[3];
      if (__ballot((a < b ? a : b) >= phase) == ~0ull) break;
    }
  }
  __syncthreads();
  asm volatile("" ::: "memory");
}

// ---------------- prep kernels ----------------
__global__ void prep_misc(const float* bihF, const float* bhhF,
                          const float* bihB, const float* bhhB, char* ws) {
  int i = blockIdx.x * blockDim.x + threadIdx.x;
  if (i < 1024) astore_u64(ws + (size_t)i * 8, 0ull);  // 8KB sync area
  if (i < GE) {
    ((float*)(ws + OFF_BF))[i] = bihF[i] + bhhF[i];
    ((float*)(ws + OFF_BB))[i] = bihB[i] + bhhB[i];
  }
  // zero enc h buffers through the bypass path
  if (i < 2 * 2 * B_ * H_ / 4) astore_u64((char*)ws + OFF_HE + (size_t)i * 8, 0ull);
}

__global__ void conv_encw(const float* WihF, const float* WhhF,
                          const float* WihB, const float* WhhB, char* ws) {
  int i = blockIdx.x * blockDim.x + threadIdx.x;
  if (i >= GE * KE) return;
  int r = i / KE, k = i - r * KE;
  float vF = (k < F_) ? WihF[r * F_ + k] : WhhF[r * H_ + (k - F_)];
  float vB = (k < F_) ? WihB[r * F_ + k] : WhhB[r * H_ + (k - F_)];
  ((_Float16*)(ws + OFF_WCF))[i] = (_Float16)vF;
  ((_Float16*)(ws + OFF_WCB))[i] = (_Float16)vB;
}

__global__ void conv_x(const float* x, char* ws) {
  int i = blockIdx.x * blockDim.x + threadIdx.x;
  if (i >= T_ * B_ * F_) return;
  int f = i & 127, b = (i >> 7) & 255, t = i >> 15;
  ((_Float16*)(ws + OFF_XH))[i] = (_Float16)x[((size_t)b * T_ + t) * F_ + f];
}

// ---------------- encoder phase (R6-proven, unchanged) ----------------
template<bool LOCAL>
DEV void encoder_phase(int dir, int chunk, int slice,
                       int tid, int wave, int quad, int col, int lane,
                       char* ws, _Float16* lds, _Float16 (*htile)[16]) {
  const _Float16* Wenc  = (const _Float16*)(ws + (dir ? OFF_WCB : OFF_WCF));
  const float*    biasE = (const float*)(ws + (dir ? OFF_BB : OFF_BF));
  const _Float16* Xh    = (const _Float16*)(ws + OFF_XH);
  _Float16* hE = (_Float16*)(ws + OFF_HE);
  _Float16* hD = (_Float16*)(ws + OFF_HDD);
  float*    cD = (float*)(ws + OFF_CD);
  unsigned* encf = (unsigned*)ws + ENCF_IDX + (dir * 4 + chunk) * 64;

  const int j0 = slice * 16;
  const int mb = chunk * 64;

  for (int it = 0; it < 20; ++it) {   // stage 64 gate rows x 640 K into LDS
    int idx = it * 256 + tid;
    int n = idx / 80, e = idx - n * 80;
    int g = n >> 4, u = n & 15;
    *((h8*)(lds + n * EPAD) + e) =
        *((const h8*)(Wenc + (size_t)(g * H_ + j0 + u) * KE) + e);
  }
  float breg[4];
#pragma unroll
  for (int g = 0; g < 4; ++g) breg[g] = biasE[g * H_ + j0 + col];
  float cst[4] = {0.f, 0.f, 0.f, 0.f};
  __syncthreads();

  // h-part B-fragments in registers
  h8 Bf[4][16];
#pragma unroll
  for (int g = 0; g < 4; ++g)
#pragma unroll
    for (int kk = 0; kk < 16; ++kk)
      Bf[g][kk] = *((const h8*)(lds + (g * 16 + col) * EPAD + F_) + kk * 4 + quad);

  const int arow = mb + wave * 16 + col;
  const int mrow = mb + wave * 16 + quad * 4;

  for (int t = 0; t < T_; ++t) {
    const int par = t & 1;
    const int tx  = dir ? (T_ - 1 - t) : t;
    f4 z = {0.f, 0.f, 0.f, 0.f};
    f4 acc[4] = {z, z, z, z};

    const h8* xr = (const h8*)(Xh + ((size_t)tx * B_ + arow) * F_);
#pragma unroll
    for (int kk = 0; kk < 4; ++kk) {
      h8 a = xr[kk * 4 + quad];
#pragma unroll
      for (int g = 0; g < 4; ++g) {
        h8 b = *((const h8*)(lds + (g * 16 + col) * EPAD) + kk * 4 + quad);
        acc[g] = __builtin_amdgcn_mfma_f32_16x16x32_f16(a, b, acc[g], 0, 0, 0);
      }
    }
    if (t > 0)
      wait_ge(encf + (lane & 31), (unsigned)t, !LOCAL, 1 << 16);
    f4 A[16];
    ld16<!LOCAL>(hE + ((size_t)(par * 2 + dir) * B_ + arow) * H_ + quad * 8, A);
#pragma unroll
    for (int kk = 0; kk < 16; ++kk) {
      h8 a = as_h8(A[kk]);
#pragma unroll
      for (int g = 0; g < 4; ++g)
        acc[g] = __builtin_amdgcn_mfma_f32_16x16x32_f16(a, Bf[g][kk], acc[g], 0, 0, 0);
    }

#pragma unroll
    for (int r = 0; r < 4; ++r) {
      float gi = acc[0][r] + breg[0];
      float gf = acc[1][r] + breg[1];
      float gg = acc[2][r] + breg[2];
      float go = acc[3][r] + breg[3];
      float c = sigm(gf) * cst[r] + sigm(gi) * tanh_(gg);
      cst[r] = c;
      float h = sigm(go) * tanh_(c);
      htile[wave * 16 + quad * 4 + r][col] = (_Float16)h;
      if (t == T_ - 1)
        astore_f32(&cD[(size_t)(mrow + r) * HD + dir * H_ + j0 + col], c);
    }
    __syncthreads();
    if (tid < 128) {
      int row = tid >> 1, half = tid & 1;
      const unsigned long long* src =
          (const unsigned long long*)&htile[row][half * 8];
      if (t < T_ - 1) {
        _Float16* dst = hE + ((size_t)((par ^ 1) * 2 + dir) * B_ + mb + row) * H_ +
                        j0 + half * 8;
        if (LOCAL) {
          ((unsigned long long*)dst)[0] = src[0];
          ((unsigned long long*)(dst + 4))[0] = src[1];
        } else {
          astore_u64(dst, src[0]);
          astore_u64(dst + 4, src[1]);
        }
      } else {
        _Float16* dst = hD + (size_t)(mb + row) * HD + dir * H_ + j0 + half * 8;
        astore_u64(dst, src[0]);
        astore_u64(dst + 4, src[1]);
      }
    }
    vm_drain();
    __syncthreads();
    if (tid == 0 && t < T_ - 1) {
      if (LOCAL) *(volatile unsigned*)(encf + slice) = (unsigned)(t + 1);
      else       astore_u32(encf + slice, (unsigned)(t + 1));
    }
  }
}

// ---------------- decoder phase (R8 structure; exchange scope per template) ----------------
template<bool LOCAL>
DEV void decoder_phase(int xcd, int rank, int tid, int wave, int quad, int col,
                       int lane, const float* dWih, const float* dWhh,
                       const float* dbih, const float* dbhh, const float* fcW,
                       const float* fcb, float* out, char* ws, _Float16* lds) {
  _Float16* hdd = (_Float16*)(ws + OFF_HDD);
  float* cD = (float*)(ws + OFF_CD);
  float* PP = (float*)(ws + OFF_PP) + (size_t)xcd * 2 * 64 * 32;  // [2 buf][64][32]
  unsigned* decf = (unsigned*)ws + DECF_IDX + xcd * 64;

  const int j0b = rank * 32;
  const int R0  = xcd * 32;
  const int m   = wave & 1;
  const int uh  = wave >> 1;
  const int unit = j0b + uh * 16 + col;
  const int arow = R0 + m * 16 + col;
  const int mrow = R0 + m * 16 + quad * 4;

  // stage gates i,f (64 rows x 1024) into LDS from source f32
  for (int it = 0; it < 64; ++it) {
    int idx = it * 256 + tid;
    int n = idx >> 8, c = idx & 255;
    int srow = (n >> 5) * HD + j0b + (n & 31);
    f4 w = *((const f4*)(dWhh + (size_t)srow * HD + c * 4));
    union { _Float16 h[4]; unsigned long long q; } u2;
#pragma unroll
    for (int i2 = 0; i2 < 4; ++i2) u2.h[i2] = (_Float16)w[i2];
    *(unsigned long long*)(lds + n * DPAD + c * 4) = u2.q;
  }
  // stage gates g,o into registers (2 x 32 h8-frags)
  h8 Bf[2][32];
#pragma unroll
  for (int gg = 0; gg < 2; ++gg)
#pragma unroll
    for (int kk = 0; kk < 32; ++kk) {
      const float* src = dWhh + (size_t)((2 + gg) * HD + unit) * HD + kk * 32 + quad * 8;
      f4 w0 = *((const f4*)src);
      f4 w1 = *((const f4*)(src + 4));
      union { _Float16 h[8]; h8 v; } u3;
#pragma unroll
      for (int i2 = 0; i2 < 4; ++i2) {
        u3.h[i2]     = (_Float16)w0[i2];
        u3.h[4 + i2] = (_Float16)w1[i2];
      }
      Bf[gg][kk] = u3.v;
    }
  float breg[4], wreg[4];
#pragma unroll
  for (int g = 0; g < 4; ++g) {
    breg[g] = dbih[g * HD + unit] + dbhh[g * HD + unit];
    wreg[g] = dWih[g * HD + unit];
  }
  const float fcw = fcW[unit];
  const float fb  = fcb[0];
  float cst[4];
#pragma unroll
  for (int r = 0; r < 4; ++r)
    cst[r] = aload_f32(cD + (size_t)(mrow + r) * HD + unit);
  __syncthreads();

  for (int l = 0; l <= L_; ++l) {
    float predv = 0.f;
    if (l > 0) {
      wait_ge(decf + (lane & 31), (unsigned)l, !LOCAL, 1 << 16);
      // reconstruct pred[row] = fcb + sum of 64 partials (step l-1 buffer)
      const float* PPr = PP + (size_t)((l - 1) & 1) * 64 * 32;
      int row = lane & 31, halfsel = lane >> 5;
      const float* pb = PPr + (size_t)(halfsel * 32) * 32 + row;
      float pv[16], s = 0.f;
      ld16s<!LOCAL>(pb, pv);
#pragma unroll
      for (int j = 0; j < 16; ++j) s += pv[j];
      ld16s<!LOCAL>(pb + 16 * 32, pv);
#pragma unroll
      for (int j = 0; j < 16; ++j) s += pv[j];
      s += __shfl_xor(s, 32);
      predv = s + fb;
      if (rank == 0 && wave == 0 && lane < 32)
        astore_f32(out + (size_t)(R0 + lane) * L_ + (l - 1), predv);
    }
    if (l == L_) break;
    const int par = l & 1;

    f4 A[32];
    const _Float16* hsrc = hdd + ((size_t)par * B_ + arow) * HD + quad * 8;
    if (l == 0 || !LOCAL) ld32<true>(hsrc, A);
    else                  ld32<false>(hsrc, A);

    f4 z = {0.f, 0.f, 0.f, 0.f};
    f4 acc[4] = {z, z, z, z};
#pragma unroll
    for (int kk = 0; kk < 32; ++kk) {
      h8 a = as_h8(A[kk]);
      h8 b0 = *((const h8*)(lds + (0 * 32 + uh * 16 + col) * DPAD) + kk * 4 + quad);
      h8 b1 = *((const h8*)(lds + (1 * 32 + uh * 16 + col) * DPAD) + kk * 4 + quad);
      acc[0] = __builtin_amdgcn_mfma_f32_16x16x32_f16(a, b0, acc[0], 0, 0, 0);
      acc[1] = __builtin_amdgcn_mfma_f32_16x16x32_f16(a, b1, acc[1], 0, 0, 0);
      acc[2] = __builtin_amdgcn_mfma_f32_16x16x32_f16(a, Bf[0][kk], acc[2], 0, 0, 0);
      acc[3] = __builtin_amdgcn_mfma_f32_16x16x32_f16(a, Bf[1][kk], acc[3], 0, 0, 0);
    }

    float pr[4], sum[4];
#pragma unroll
    for (int r = 0; r < 4; ++r)
      pr[r] = (l > 0) ? __shfl(predv, m * 16 + quad * 4 + r) : 0.f;
#pragma unroll
    for (int r = 0; r < 4; ++r) {
      float gi = acc[0][r] + breg[0] + pr[r] * wreg[0];
      float gf = acc[1][r] + breg[1] + pr[r] * wreg[1];
      float gg = acc[2][r] + breg[2] + pr[r] * wreg[2];
      float go = acc[3][r] + breg[3] + pr[r] * wreg[3];
      float c = sigm(gf) * cst[r] + sigm(gi) * tanh_(gg);
      cst[r] = c;
      float h = sigm(go) * tanh_(c);
      size_t hoff = ((size_t)(par ^ 1) * B_ + mrow + r) * HD + unit;
      if (LOCAL) hdd[hoff] = (_Float16)h;
      else       astore_u16(hdd + hoff, (_Float16)h);
      sum[r] = h * fcw;
    }
#pragma unroll
    for (int off = 1; off < 16; off <<= 1) {
#pragma unroll
      for (int r = 0; r < 4; ++r) sum[r] += __shfl_xor(sum[r], off, 16);
    }
    if (col == 0) {
      float* PPw = PP + (size_t)(l & 1) * 64 * 32;   // step-l buffer
      float* pdst = PPw + (size_t)(rank * 2 + uh) * 32 + m * 16 + quad * 4;
      if (LOCAL) {
        f4 v = {sum[0], sum[1], sum[2], sum[3]};
        *(f4*)pdst = v;
      } else {
        union { float f[4]; unsigned long long q[2]; } u5;
#pragma unroll
        for (int r = 0; r < 4; ++r) u5.f[r] = sum[r];
        astore_u64(pdst, u5.q[0]);
        astore_u64(pdst + 2, u5.q[1]);
      }
    }
    vm_drain();
    __syncthreads();
    if (tid == 0) {
      if (LOCAL) *(volatile unsigned*)(decf + rank) = (unsigned)(l + 1);
      else       astore_u32(decf + rank, (unsigned)(l + 1));
    }
  }
}

// ---------------- persistent RNN kernel ----------------
__global__ __launch_bounds__(256, 1)
void rnn_kernel(const float* __restrict__ dWih, const float* __restrict__ dWhh,
                const float* __restrict__ dbih, const float* __restrict__ dbhh,
                const float* __restrict__ fcW, const float* __restrict__ fcb,
                float* __restrict__ out, char* __restrict__ ws) {
  __shared__ __align__(16) _Float16 lds[64 * DPAD];   // 132096 B
  __shared__ __align__(16) _Float16 htile[64][16];    // 2 KB
  __shared__ int sh[2];

  const int tid  = threadIdx.x;
  const int wave = tid >> 6;
  const int lane = tid & 63;
  const int quad = lane >> 4;
  const int col  = lane & 15;
  const int bi   = blockIdx.x;

  unsigned* sync  = (unsigned*)(ws + OFF_SYNC);
  unsigned* fl    = sync + FL256_IDX;
  unsigned* claim = sync + CLAIM_IDX;

  // ---- physical placement discovery ----
  if (tid == 0) {
    unsigned x;
    asm volatile("s_getreg_b32 %0, hwreg(HW_REG_XCC_ID)" : "=s"(x));
    int xcd = (int)(x & 7u);
    unsigned r = __hip_atomic_fetch_add(claim + xcd * 64, 1u, __ATOMIC_RELAXED,
                                        __HIP_MEMORY_SCOPE_AGENT);
    sh[0] = xcd;
    sh[1] = (int)r;
  }
  __syncthreads();
  const int xcd = sh[0], rank = sh[1];
  gsync(fl, bi, 1u, tid);  // all claims done
  if (tid == 0) {
    int d = 0;
    for (int k = 0; k < 8; ++k)
      if (aload_u32(claim + k * 64) != 32u) d = 1;
    sh[0] = d;
  }
  __syncthreads();
  const bool deg = (sh[0] != 0) || (rank >= 32);

  if (!deg)
    encoder_phase<true>(xcd >> 2, xcd & 3, rank, tid, wave, quad, col, lane,
                        ws, lds, htile);
  else
    encoder_phase<false>(bi >> 7, bi & 3, (bi & 127) >> 2, tid, wave, quad, col,
                         lane, ws, lds, htile);

  gsync(fl, bi, 2u, tid);  // encoder -> decoder handoff (hD/cD via L3)

  // R9 BISECTION: decoder exchange forced to DEEP (agent/L3) in BOTH paths.
  // Keep physical-XCD domain assignment for the non-deg path (L3 locality).
  if (!deg)
    decoder_phase<false>(xcd, rank, tid, wave, quad, col, lane, dWih, dWhh,
                         dbih, dbhh, fcW, fcb, out, ws, lds);
  else
    decoder_phase<false>(bi >> 5, bi & 31, tid, wave, quad, col, lane, dWih,
                         dWhh, dbih, dbhh, fcW, fcb, out, ws, lds);
}

extern "C" void kernel_launch(void* const* d_in, const int* in_sizes, int n_in,
                              void* d_out, int out_size, void* d_ws, size_t ws_size,
                              hipStream_t stream) {
  const float* x     = (const float*)d_in[0];
  const float* eWihF = (const float*)d_in[1];
  const float* eWhhF = (const float*)d_in[2];
  const float* ebihF = (const float*)d_in[3];
  const float* ebhhF = (const float*)d_in[4];
  const float* eWihB = (const float*)d_in[5];
  const float* eWhhB = (const float*)d_in[6];
  const float* ebihB = (const float*)d_in[7];
  const float* ebhhB = (const float*)d_in[8];
  const float* dWih  = (const float*)d_in[9];
  const float* dWhh  = (const float*)d_in[10];
  const float* dbih  = (const float*)d_in[11];
  const float* dbhh  = (const float*)d_in[12];
  const float* fcW   = (const float*)d_in[13];
  const float* fcb   = (const float*)d_in[14];
  float* out = (float*)d_out;
  char*  ws  = (char*)d_ws;

  prep_misc<<<512, 256, 0, stream>>>(ebihF, ebhhF, ebihB, ebhhB, ws);
  conv_encw<<<(GE * KE) / 256, 256, 0, stream>>>(eWihF, eWhhF, eWihB, eWhhB, ws);
  conv_x<<<(T_ * B_ * F_) / 256, 256, 0, stream>>>(x, ws);

  void* args[] = {(void*)&dWih, (void*)&dWhh, (void*)&dbih, (void*)&dbhh,
                  (void*)&fcW,  (void*)&fcb,  (void*)&out,  (void*)&ws};
  hipError_t err = hipLaunchCooperativeKernel(rnn_kernel, dim3(256), dim3(256),
                                              args, 0, stream);
  if (err != hipSuccess) {
    rnn_kernel<<<dim3(256), dim3(256), 0, stream>>>(dWih, dWhh, dbih, dbhh,
                                                    fcW, fcb, out, ws);
  }
}